// Round 2
// baseline (760.764 us; speedup 1.0000x reference)
//
#include <hip/hip_runtime.h>
#include <stdint.h>

// Problem constants (from reference)
#define KCB 4096
#define DIM 128
#define BSZ 8
#define TLEN 3000
#define NPT 24000            // BSZ*TLEN
#define KD (KCB*DIM)         // 524288
#define BDT (BSZ*DIM*TLEN)   // 3072000

// Output layout (floats, concatenated in reference return order)
#define OFF_ZQ    0
#define OFF_CODES 3072000
#define OFF_LOSS  3096000
#define OFF_CB    3096001
#define OFF_CS    3620289
#define OFF_EA    3624385

// Workspace layout (in float units)
#define WS_LOSS   0
#define WS_NTOT   1
#define WS_Y2     16
#define WS_COUNTS (16 + KCB)
#define WS_CS0    (16 + 2*KCB)
#define WS_RAND   (16 + 3*KCB)   // uint32[KCB]
#define WS_IDX    (16 + 4*KCB)   // int32[NPT]

// ---------------- threefry2x32-20 (JAX-compatible) ----------------
__device__ __forceinline__ void threefry2x32(uint32_t k0, uint32_t k1,
                                             uint32_t x0, uint32_t x1,
                                             uint32_t& o0, uint32_t& o1) {
  const uint32_t ks0 = k0, ks1 = k1, ks2 = k0 ^ k1 ^ 0x1BD11BDAu;
  const int r0[4] = {13, 15, 26, 6};
  const int r1[4] = {17, 29, 16, 24};
  x0 += ks0; x1 += ks1;
  #pragma unroll
  for (int i = 0; i < 5; ++i) {
    #pragma unroll
    for (int j = 0; j < 4; ++j) {
      int r = (i & 1) ? r1[j] : r0[j];
      x0 += x1;
      x1 = (x1 << r) | (x1 >> (32 - r));
      x1 ^= x0;
    }
    uint32_t ia = (uint32_t)((i + 1) % 3), ib = (uint32_t)((i + 2) % 3);
    uint32_t a = (ia == 0) ? ks0 : (ia == 1) ? ks1 : ks2;
    uint32_t b = (ib == 0) ? ks0 : (ib == 1) ? ks1 : ks2;
    x0 += a;
    x1 += b + (uint32_t)(i + 1);
  }
  o0 = x0; o1 = x1;
}

// numpy pairwise sum (n=128, PW_BLOCKSIZE branch): 8 accumulators over
// separately-rounded products a[d]=fl(v[d]*v[d]), combine tree
// ((r0+r1)+(r2+r3))+((r4+r5)+(r6+r7)). No FMA, no reassociation.
__device__ __forceinline__ float np_sumsq_128(const float* __restrict__ v) {
  float r[8];
  #pragma unroll
  for (int j = 0; j < 8; ++j) r[j] = __fmul_rn(v[j], v[j]);
  #pragma unroll
  for (int i = 8; i < DIM; i += 8) {
    #pragma unroll
    for (int j = 0; j < 8; ++j)
      r[j] = __fadd_rn(r[j], __fmul_rn(v[i + j], v[i + j]));
  }
  return __fadd_rn(__fadd_rn(__fadd_rn(r[0], r[1]), __fadd_rn(r[2], r[3])),
                   __fadd_rn(__fadd_rn(r[4], r[5]), __fadd_rn(r[6], r[7])));
}

// ---------------- kernel: y2[k] = ||codebook[k]||^2 (numpy-pairwise) --------
__global__ void y2_kernel(const float* __restrict__ cb, float* __restrict__ y2) {
  int k = blockIdx.x * 256 + threadIdx.x;
  if (k >= KCB) return;
  y2[k] = np_sumsq_128(cb + (size_t)k * DIM);
}

// ---------------- kernel: out_ea = 0.99 * ema_embed_avg ----------------
__global__ void ea_init_kernel(const float* __restrict__ ema_ea, float* __restrict__ out_ea) {
  int i = blockIdx.x * 256 + threadIdx.x;
  out_ea[i] = 0.99f * ema_ea[i];
}

// ---------------- kernel: fused distance GEMM + argmin (np-fp32 bitwise) ----
// grid = NPT/64 = 375 blocks, 256 threads. LDS tiles: z 64x128, cb 64x128 (padded).
// Distances reproduce numpy fp32 exactly: M = serial ascending-k FMA (sgemm),
// dist = fl(fl(x2+y2) - 2*M); argmin = first occurrence of min.
__launch_bounds__(256)
__global__ void argmin_kernel(const float* __restrict__ z, const float* __restrict__ cb,
                              const float* __restrict__ y2g,
                              int* __restrict__ idx_out, float* __restrict__ codes_out) {
  __shared__ float zt[64 * 132];
  __shared__ float ct[64 * 132];
  __shared__ float x2s[64];
  __shared__ float y2s[64];

  const int tid = threadIdx.x;
  const int n0 = blockIdx.x * 64;

  // ---- stage z tile: z_flat[n][d] = z[b*D*T + d*T + t], n = b*T + t
  {
    int nl = tid & 63, dd = tid >> 6;
    int n = n0 + nl;
    int b = n / TLEN, t = n - b * TLEN;
    const float* zbase = z + (size_t)b * (DIM * TLEN) + t;
    #pragma unroll
    for (int d = dd; d < DIM; d += 4) zt[nl * 132 + d] = zbase[(size_t)d * TLEN];
  }
  __syncthreads();
  if (tid < 64) x2s[tid] = np_sumsq_128(zt + tid * 132);   // numpy-pairwise x2

  const int tn = tid >> 4;   // 0..15 -> n rows {tn, tn+16, tn+32, tn+48}
  const int tk = tid & 15;   // 0..15 -> k rows {tk, tk+16, tk+32, tk+48} within chunk

  float bv[4];
  int   bi[4];
  #pragma unroll
  for (int i = 0; i < 4; ++i) { bv[i] = 3.402823466e+38f; bi[i] = 0x7FFFFFFF; }

  for (int c = 0; c < KCB / 64; ++c) {
    const int k0 = c * 64;
    // stage codebook chunk (64 rows x 128) + y2 chunk
    #pragma unroll
    for (int it = 0; it < 8; ++it) {
      int f = it * 256 + tid;            // float4 index, 0..2047
      int row = f >> 5, col = f & 31;
      *reinterpret_cast<float4*>(ct + row * 132 + col * 4) =
          *reinterpret_cast<const float4*>(cb + (size_t)(k0 + row) * DIM + col * 4);
    }
    if (tid < 16)
      *reinterpret_cast<float4*>(y2s + tid * 4) =
          *reinterpret_cast<const float4*>(y2g + k0 + tid * 4);
    __syncthreads();

    float acc[4][4];
    #pragma unroll
    for (int i = 0; i < 4; ++i)
      #pragma unroll
      for (int j = 0; j < 4; ++j) acc[i][j] = 0.f;

    // serial ascending-d FMA chain per (i,j) — matches sgemm accumulation
    #pragma unroll 4
    for (int d4 = 0; d4 < 32; ++d4) {
      float4 za[4], cbv[4];
      #pragma unroll
      for (int i = 0; i < 4; ++i)
        za[i] = *reinterpret_cast<const float4*>(zt + (tn + 16 * i) * 132 + d4 * 4);
      #pragma unroll
      for (int j = 0; j < 4; ++j)
        cbv[j] = *reinterpret_cast<const float4*>(ct + (tk + 16 * j) * 132 + d4 * 4);
      #pragma unroll
      for (int i = 0; i < 4; ++i)
        #pragma unroll
        for (int j = 0; j < 4; ++j) {
          acc[i][j] = __fmaf_rn(za[i].x, cbv[j].x, acc[i][j]);
          acc[i][j] = __fmaf_rn(za[i].y, cbv[j].y, acc[i][j]);
          acc[i][j] = __fmaf_rn(za[i].z, cbv[j].z, acc[i][j]);
          acc[i][j] = __fmaf_rn(za[i].w, cbv[j].w, acc[i][j]);
        }
    }

    #pragma unroll
    for (int i = 0; i < 4; ++i) {
      float x2v = x2s[tn + 16 * i];
      #pragma unroll
      for (int j = 0; j < 4; ++j) {
        int k = k0 + tk + 16 * j;
        // dist = fl(fl(x2+y2) - 2*M) — numpy op order, no contraction
        float t1 = __fadd_rn(x2v, y2s[tk + 16 * j]);
        float dist = __fsub_rn(t1, __fmul_rn(2.0f, acc[i][j]));
        if (dist < bv[i]) { bv[i] = dist; bi[i] = k; }   // strict < + ascending k
      }
    }
    __syncthreads();
  }

  // cross-lane argmin merge over the 16 tk lanes (value, then smaller index)
  #pragma unroll
  for (int m = 1; m < 16; m <<= 1) {
    #pragma unroll
    for (int i = 0; i < 4; ++i) {
      float ov = __shfl_xor(bv[i], m);
      int   oi = __shfl_xor(bi[i], m);
      if (ov < bv[i] || (ov == bv[i] && oi < bi[i])) { bv[i] = ov; bi[i] = oi; }
    }
  }

  if (tk == 0) {
    #pragma unroll
    for (int i = 0; i < 4; ++i) {
      int n = n0 + tn + 16 * i;
      idx_out[n] = bi[i];
      codes_out[n] = (float)bi[i];
    }
  }
}

// ---------------- kernel: gather z_q, commit-loss, segment sums ----------------
__global__ void gather_kernel(const float* __restrict__ z, const float* __restrict__ cb,
                              const int* __restrict__ idx,
                              float* __restrict__ zq_out, float* __restrict__ ea_out,
                              float* __restrict__ counts, float* __restrict__ loss_ws) {
  int i = blockIdx.x * 256 + threadIdx.x;   // i < BDT, layout [B][D][T]
  int t = i % TLEN;
  int bd = i / TLEN;
  int d = bd & (DIM - 1);
  int b = bd >> 7;
  int n = b * TLEN + t;
  int k = idx[n];
  float zv = z[i];
  float q = cb[(size_t)k * DIM + d];
  zq_out[i] = q;                 // STE output == q in value (diff ~1e-7 ok)
  float diff = zv - q;
  float sq = diff * diff;
  #pragma unroll
  for (int m = 1; m <= 32; m <<= 1) sq += __shfl_xor(sq, m);
  __shared__ float ps[4];
  if ((threadIdx.x & 63) == 0) ps[threadIdx.x >> 6] = sq;
  __syncthreads();
  if (threadIdx.x == 0) atomicAdd(loss_ws, ps[0] + ps[1] + ps[2] + ps[3]);
  atomicAdd(ea_out + (size_t)k * DIM + d, 0.01f * zv);
  if (d == 0) atomicAdd(counts + k, 1.0f);
}

// ---------------- kernel: new_cs0, n_tot, threefry rand_idx ----------------
__global__ void cs_rand_kernel(const float* __restrict__ ema_cs, const float* __restrict__ counts,
                               float* __restrict__ cs0, uint32_t* __restrict__ rnd,
                               float* __restrict__ ntot) {
  int k = blockIdx.x * 256 + threadIdx.x;
  float v = 0.99f * ema_cs[k] + 0.01f * counts[k];
  cs0[k] = v;

  // jax.random.randint(key(42), (K,), 0, 24000), int32:
  //   bits = random_bits(key, 32, (K,)) — partitionable: o0^o1 of TF((0,42),(0,k))
  //   hi = bits>>16, lo = bits&0xffff, mult = 2^32 % span
  //   off = ((hi%span)*mult + lo%span) % span
  uint32_t o0, o1;
  threefry2x32(0u, 42u, 0u, (uint32_t)k, o0, o1);
  uint32_t bits = o0 ^ o1;
  uint32_t hi = bits >> 16, lo = bits & 0xffffu;
  const uint32_t span = 24000u, mult = 23296u;  // 2^32 % 24000
  uint32_t off = ((hi % span) * mult + (lo % span)) % span;
  rnd[k] = off;

  float s = v;
  #pragma unroll
  for (int m = 1; m <= 32; m <<= 1) s += __shfl_xor(s, m);
  __shared__ float ps[4];
  if ((threadIdx.x & 63) == 0) ps[threadIdx.x >> 6] = s;
  __syncthreads();
  if (threadIdx.x == 0) atomicAdd(ntot, ps[0] + ps[1] + ps[2] + ps[3]);
}

// ---------------- kernel: finalize codebook / cs / ea / loss ----------------
__global__ void finalize_kernel(const float* __restrict__ z, const float* __restrict__ cs0_ws,
                                const uint32_t* __restrict__ rnd,
                                const float* __restrict__ ntot_ws, const float* __restrict__ loss_ws,
                                float* __restrict__ out) {
  int i = blockIdx.x * 256 + threadIdx.x;   // i < KD
  int k = i >> 7, d = i & (DIM - 1);
  float cs0 = cs0_ws[k];
  float ntot = *ntot_ws;
  float* ea = out + OFF_EA;
  float ea0 = ea[i];
  float csz = (cs0 + 1e-5f) / (ntot + (float)KCB * 1e-5f) * ntot;
  float embed = ea0 / fmaxf(csz, 1e-12f);
  bool dead = cs0 < 2.0f;
  uint32_t rn = rnd[k];
  int bb = (int)(rn / TLEN), tt = (int)(rn % TLEN);
  float sampled = z[(size_t)bb * (DIM * TLEN) + (size_t)d * TLEN + tt];
  out[OFF_CB + i] = dead ? sampled : embed;
  ea[i] = dead ? sampled : ea0;
  if (d == 0) out[OFF_CS + k] = dead ? 1.0f : cs0;
  if (i == 0) out[OFF_LOSS] = (*loss_ws) * (1.0f / (float)BDT);
}

extern "C" void kernel_launch(void* const* d_in, const int* in_sizes, int n_in,
                              void* d_out, int out_size, void* d_ws, size_t ws_size,
                              hipStream_t stream) {
  const float* z      = (const float*)d_in[0];
  const float* cb     = (const float*)d_in[1];
  const float* ema_cs = (const float*)d_in[2];
  const float* ema_ea = (const float*)d_in[3];
  float* out = (float*)d_out;
  float* wsf = (float*)d_ws;

  // zero loss, ntot, y2, counts
  hipMemsetAsync(d_ws, 0, (size_t)(16 + 2 * KCB) * sizeof(float), stream);

  y2_kernel<<<KCB / 256, 256, 0, stream>>>(cb, wsf + WS_Y2);
  ea_init_kernel<<<KD / 256, 256, 0, stream>>>(ema_ea, out + OFF_EA);
  argmin_kernel<<<NPT / 64, 256, 0, stream>>>(z, cb, wsf + WS_Y2,
                                              (int*)(wsf + WS_IDX), out + OFF_CODES);
  gather_kernel<<<BDT / 256, 256, 0, stream>>>(z, cb, (int*)(wsf + WS_IDX),
                                               out + OFF_ZQ, out + OFF_EA,
                                               wsf + WS_COUNTS, wsf + WS_LOSS);
  cs_rand_kernel<<<KCB / 256, 256, 0, stream>>>(ema_cs, wsf + WS_COUNTS,
                                                wsf + WS_CS0, (uint32_t*)(wsf + WS_RAND),
                                                wsf + WS_NTOT);
  finalize_kernel<<<KD / 256, 256, 0, stream>>>(z, wsf + WS_CS0, (uint32_t*)(wsf + WS_RAND),
                                                wsf + WS_NTOT, wsf + WS_LOSS, out);
}

// Round 3
// 712.227 us; speedup vs baseline: 1.0681x; 1.0681x over previous
//
#include <hip/hip_runtime.h>
#include <stdint.h>

// Problem constants (from reference)
#define KCB 4096
#define DIM 128
#define BSZ 8
#define TLEN 3000
#define NPT 24000            // BSZ*TLEN
#define KD (KCB*DIM)         // 524288
#define BDT (BSZ*DIM*TLEN)   // 3072000

#define KSPLIT 4
#define KSEG (KCB / KSPLIT)  // 1024 codes per block
#define NCHUNK (KSEG / 64)   // 16 chunks of 64

// Output layout (floats, concatenated in reference return order)
#define OFF_ZQ    0
#define OFF_CODES 3072000
#define OFF_LOSS  3096000
#define OFF_CB    3096001
#define OFF_CS    3620289
#define OFF_EA    3624385

// Workspace layout (in float units)
#define WS_LOSS   0
#define WS_NTOT   1
#define WS_Y2     16
#define WS_COUNTS (16 + KCB)
#define WS_CS0    (16 + 2*KCB)
#define WS_RAND   (16 + 3*KCB)           // uint32[KCB]
#define WS_IDX    (16 + 4*KCB)           // int32[NPT]
#define WS_PBV    (WS_IDX + NPT)         // float[KSPLIT*NPT]
#define WS_PBI    (WS_PBV + KSPLIT*NPT)  // int32[KSPLIT*NPT]

// ---------------- threefry2x32-20 (JAX-compatible) ----------------
__device__ __forceinline__ void threefry2x32(uint32_t k0, uint32_t k1,
                                             uint32_t x0, uint32_t x1,
                                             uint32_t& o0, uint32_t& o1) {
  const uint32_t ks0 = k0, ks1 = k1, ks2 = k0 ^ k1 ^ 0x1BD11BDAu;
  const int r0[4] = {13, 15, 26, 6};
  const int r1[4] = {17, 29, 16, 24};
  x0 += ks0; x1 += ks1;
  #pragma unroll
  for (int i = 0; i < 5; ++i) {
    #pragma unroll
    for (int j = 0; j < 4; ++j) {
      int r = (i & 1) ? r1[j] : r0[j];
      x0 += x1;
      x1 = (x1 << r) | (x1 >> (32 - r));
      x1 ^= x0;
    }
    uint32_t ia = (uint32_t)((i + 1) % 3), ib = (uint32_t)((i + 2) % 3);
    uint32_t a = (ia == 0) ? ks0 : (ia == 1) ? ks1 : ks2;
    uint32_t b = (ib == 0) ? ks0 : (ib == 1) ? ks1 : ks2;
    x0 += a;
    x1 += b + (uint32_t)(i + 1);
  }
  o0 = x0; o1 = x1;
}

// numpy pairwise sum (n=128): 8 accumulators over separately-rounded
// products, combine ((r0+r1)+(r2+r3))+((r4+r5)+(r6+r7)). No FMA.
__device__ __forceinline__ float np_sumsq_128(const float* __restrict__ v) {
  float r[8];
  #pragma unroll
  for (int j = 0; j < 8; ++j) r[j] = __fmul_rn(v[j], v[j]);
  #pragma unroll
  for (int i = 8; i < DIM; i += 8) {
    #pragma unroll
    for (int j = 0; j < 8; ++j)
      r[j] = __fadd_rn(r[j], __fmul_rn(v[i + j], v[i + j]));
  }
  return __fadd_rn(__fadd_rn(__fadd_rn(r[0], r[1]), __fadd_rn(r[2], r[3])),
                   __fadd_rn(__fadd_rn(r[4], r[5]), __fadd_rn(r[6], r[7])));
}

// ---------------- kernel: y2[k] = ||codebook[k]||^2 (numpy-pairwise) --------
__global__ void y2_kernel(const float* __restrict__ cb, float* __restrict__ y2) {
  int k = blockIdx.x * 256 + threadIdx.x;
  if (k >= KCB) return;
  y2[k] = np_sumsq_128(cb + (size_t)k * DIM);
}

// ---------------- kernel: out_ea = 0.99 * ema_embed_avg ----------------
__global__ void ea_init_kernel(const float* __restrict__ ema_ea, float* __restrict__ out_ea) {
  int i = blockIdx.x * 256 + threadIdx.x;
  out_ea[i] = 0.99f * ema_ea[i];
}

// ---------------- kernel: fused distance GEMM + argmin (np-fp32 bitwise) ----
// grid = (375, KSPLIT). Each block: 64 n-rows x KSEG codes.
// Register-staged double buffer on the codebook chunk hides L2 latency.
__launch_bounds__(256)
__global__ void argmin_kernel(const float* __restrict__ z, const float* __restrict__ cb,
                              const float* __restrict__ y2g,
                              float* __restrict__ pbv, int* __restrict__ pbi) {
  __shared__ float zt[64 * 132];
  __shared__ float ct[64 * 132];
  __shared__ float x2s[64];
  __shared__ float y2s[64];

  const int tid = threadIdx.x;
  const int n0 = blockIdx.x * 64;
  const int ks0 = blockIdx.y * KSEG;

  // ---- stage z tile: z_flat[n][d] = z[b*D*T + d*T + t], n = b*T + t
  {
    int nl = tid & 63, dd = tid >> 6;
    int n = n0 + nl;
    int b = n / TLEN, t = n - b * TLEN;
    const float* zbase = z + (size_t)b * (DIM * TLEN) + t;
    #pragma unroll
    for (int d = dd; d < DIM; d += 4) zt[nl * 132 + d] = zbase[(size_t)d * TLEN];
  }

  // staging map for codebook chunk: thread covers 8 float4 slots
  const int srow = tid >> 5;           // 0..7  (+8 per iter)
  const int scol = tid & 31;           // float4 col 0..31

  // prologue: load chunk 0 into regs
  float4 rbuf[8];
  {
    const float* src = cb + (size_t)ks0 * DIM;
    #pragma unroll
    for (int it = 0; it < 8; ++it)
      rbuf[it] = *reinterpret_cast<const float4*>(src + (size_t)(it * 8 + srow) * DIM + scol * 4);
  }

  __syncthreads();
  if (tid < 64) x2s[tid] = np_sumsq_128(zt + tid * 132);   // numpy-pairwise x2

  const int tn = tid >> 4;   // 0..15 -> n rows {tn, tn+16, tn+32, tn+48}
  const int tk = tid & 15;   // 0..15 -> k rows {tk, tk+16, tk+32, tk+48} within chunk

  float bv[4];
  int   bi[4];
  #pragma unroll
  for (int i = 0; i < 4; ++i) { bv[i] = 3.402823466e+38f; bi[i] = 0x7FFFFFFF; }

  for (int c = 0; c < NCHUNK; ++c) {
    const int k0 = ks0 + c * 64;
    // commit staged regs to LDS
    #pragma unroll
    for (int it = 0; it < 8; ++it)
      *reinterpret_cast<float4*>(ct + (it * 8 + srow) * 132 + scol * 4) = rbuf[it];
    if (tid < 16)
      *reinterpret_cast<float4*>(y2s + tid * 4) =
          *reinterpret_cast<const float4*>(y2g + k0 + tid * 4);
    __syncthreads();

    // issue next chunk's loads (overlap with compute below)
    if (c + 1 < NCHUNK) {
      const float* src = cb + (size_t)(k0 + 64) * DIM;
      #pragma unroll
      for (int it = 0; it < 8; ++it)
        rbuf[it] = *reinterpret_cast<const float4*>(src + (size_t)(it * 8 + srow) * DIM + scol * 4);
    }

    float acc[4][4];
    #pragma unroll
    for (int i = 0; i < 4; ++i)
      #pragma unroll
      for (int j = 0; j < 4; ++j) acc[i][j] = 0.f;

    // serial ascending-d FMA chain per (i,j) — matches sgemm accumulation
    #pragma unroll 4
    for (int d4 = 0; d4 < 32; ++d4) {
      float4 za[4], cbv[4];
      #pragma unroll
      for (int i = 0; i < 4; ++i)
        za[i] = *reinterpret_cast<const float4*>(zt + (tn + 16 * i) * 132 + d4 * 4);
      #pragma unroll
      for (int j = 0; j < 4; ++j)
        cbv[j] = *reinterpret_cast<const float4*>(ct + (tk + 16 * j) * 132 + d4 * 4);
      #pragma unroll
      for (int i = 0; i < 4; ++i)
        #pragma unroll
        for (int j = 0; j < 4; ++j) {
          acc[i][j] = __fmaf_rn(za[i].x, cbv[j].x, acc[i][j]);
          acc[i][j] = __fmaf_rn(za[i].y, cbv[j].y, acc[i][j]);
          acc[i][j] = __fmaf_rn(za[i].z, cbv[j].z, acc[i][j]);
          acc[i][j] = __fmaf_rn(za[i].w, cbv[j].w, acc[i][j]);
        }
    }

    #pragma unroll
    for (int i = 0; i < 4; ++i) {
      float x2v = x2s[tn + 16 * i];
      #pragma unroll
      for (int j = 0; j < 4; ++j) {
        int k = k0 + tk + 16 * j;
        // dist = fl(fl(x2+y2) - 2*M) — numpy op order, no contraction
        float t1 = __fadd_rn(x2v, y2s[tk + 16 * j]);
        float dist = __fsub_rn(t1, __fmul_rn(2.0f, acc[i][j]));
        if (dist < bv[i]) { bv[i] = dist; bi[i] = k; }   // strict < + ascending k
      }
    }
    __syncthreads();
  }

  // cross-lane argmin merge over the 16 tk lanes (value, then smaller index)
  #pragma unroll
  for (int m = 1; m < 16; m <<= 1) {
    #pragma unroll
    for (int i = 0; i < 4; ++i) {
      float ov = __shfl_xor(bv[i], m);
      int   oi = __shfl_xor(bi[i], m);
      if (ov < bv[i] || (ov == bv[i] && oi < bi[i])) { bv[i] = ov; bi[i] = oi; }
    }
  }

  if (tk == 0) {
    #pragma unroll
    for (int i = 0; i < 4; ++i) {
      int n = n0 + tn + 16 * i;
      pbv[(size_t)blockIdx.y * NPT + n] = bv[i];
      pbi[(size_t)blockIdx.y * NPT + n] = bi[i];
    }
  }
}

// ---------------- kernel: merge K-split partials ----------------
__global__ void merge_kernel(const float* __restrict__ pbv, const int* __restrict__ pbi,
                             int* __restrict__ idx_out, float* __restrict__ codes_out) {
  int n = blockIdx.x * 256 + threadIdx.x;
  if (n >= NPT) return;
  float bv = pbv[n];
  int bi = pbi[n];
  #pragma unroll
  for (int s = 1; s < KSPLIT; ++s) {
    float v = pbv[(size_t)s * NPT + n];
    int i2 = pbi[(size_t)s * NPT + n];
    if (v < bv) { bv = v; bi = i2; }   // ascending split order: ties keep earlier k
  }
  idx_out[n] = bi;
  codes_out[n] = (float)bi;
}

// ---------------- kernel: gather z_q, commit-loss, segment sums ----------------
__global__ void gather_kernel(const float* __restrict__ z, const float* __restrict__ cb,
                              const int* __restrict__ idx,
                              float* __restrict__ zq_out, float* __restrict__ ea_out,
                              float* __restrict__ counts, float* __restrict__ loss_ws) {
  int i = blockIdx.x * 256 + threadIdx.x;   // i < BDT, layout [B][D][T]
  int t = i % TLEN;
  int bd = i / TLEN;
  int d = bd & (DIM - 1);
  int b = bd >> 7;
  int n = b * TLEN + t;
  int k = idx[n];
  float zv = z[i];
  float q = cb[(size_t)k * DIM + d];
  zq_out[i] = q;                 // STE output == q in value
  float diff = zv - q;
  float sq = diff * diff;
  #pragma unroll
  for (int m = 1; m <= 32; m <<= 1) sq += __shfl_xor(sq, m);
  __shared__ float ps[4];
  if ((threadIdx.x & 63) == 0) ps[threadIdx.x >> 6] = sq;
  __syncthreads();
  if (threadIdx.x == 0) atomicAdd(loss_ws, ps[0] + ps[1] + ps[2] + ps[3]);
  atomicAdd(ea_out + (size_t)k * DIM + d, 0.01f * zv);
  if (d == 0) atomicAdd(counts + k, 1.0f);
}

// ---------------- kernel: new_cs0, n_tot, threefry rand_idx ----------------
__global__ void cs_rand_kernel(const float* __restrict__ ema_cs, const float* __restrict__ counts,
                               float* __restrict__ cs0, uint32_t* __restrict__ rnd,
                               float* __restrict__ ntot) {
  int k = blockIdx.x * 256 + threadIdx.x;
  float v = 0.99f * ema_cs[k] + 0.01f * counts[k];
  cs0[k] = v;

  uint32_t o0, o1;
  threefry2x32(0u, 42u, 0u, (uint32_t)k, o0, o1);
  uint32_t bits = o0 ^ o1;
  uint32_t hi = bits >> 16, lo = bits & 0xffffu;
  const uint32_t span = 24000u, mult = 23296u;  // 2^32 % 24000
  uint32_t off = ((hi % span) * mult + (lo % span)) % span;
  rnd[k] = off;

  float s = v;
  #pragma unroll
  for (int m = 1; m <= 32; m <<= 1) s += __shfl_xor(s, m);
  __shared__ float ps[4];
  if ((threadIdx.x & 63) == 0) ps[threadIdx.x >> 6] = s;
  __syncthreads();
  if (threadIdx.x == 0) atomicAdd(ntot, ps[0] + ps[1] + ps[2] + ps[3]);
}

// ---------------- kernel: finalize codebook / cs / ea / loss ----------------
__global__ void finalize_kernel(const float* __restrict__ z, const float* __restrict__ cs0_ws,
                                const uint32_t* __restrict__ rnd,
                                const float* __restrict__ ntot_ws, const float* __restrict__ loss_ws,
                                float* __restrict__ out) {
  int i = blockIdx.x * 256 + threadIdx.x;   // i < KD
  int k = i >> 7, d = i & (DIM - 1);
  float cs0 = cs0_ws[k];
  float ntot = *ntot_ws;
  float* ea = out + OFF_EA;
  float ea0 = ea[i];
  float csz = (cs0 + 1e-5f) / (ntot + (float)KCB * 1e-5f) * ntot;
  float embed = ea0 / fmaxf(csz, 1e-12f);
  bool dead = cs0 < 2.0f;
  uint32_t rn = rnd[k];
  int bb = (int)(rn / TLEN), tt = (int)(rn % TLEN);
  float sampled = z[(size_t)bb * (DIM * TLEN) + (size_t)d * TLEN + tt];
  out[OFF_CB + i] = dead ? sampled : embed;
  ea[i] = dead ? sampled : ea0;
  if (d == 0) out[OFF_CS + k] = dead ? 1.0f : cs0;
  if (i == 0) out[OFF_LOSS] = (*loss_ws) * (1.0f / (float)BDT);
}

extern "C" void kernel_launch(void* const* d_in, const int* in_sizes, int n_in,
                              void* d_out, int out_size, void* d_ws, size_t ws_size,
                              hipStream_t stream) {
  const float* z      = (const float*)d_in[0];
  const float* cb     = (const float*)d_in[1];
  const float* ema_cs = (const float*)d_in[2];
  const float* ema_ea = (const float*)d_in[3];
  float* out = (float*)d_out;
  float* wsf = (float*)d_ws;

  // zero loss, ntot, y2, counts
  hipMemsetAsync(d_ws, 0, (size_t)(16 + 2 * KCB) * sizeof(float), stream);

  y2_kernel<<<KCB / 256, 256, 0, stream>>>(cb, wsf + WS_Y2);
  ea_init_kernel<<<KD / 256, 256, 0, stream>>>(ema_ea, out + OFF_EA);
  dim3 agrid(NPT / 64, KSPLIT);
  argmin_kernel<<<agrid, 256, 0, stream>>>(z, cb, wsf + WS_Y2,
                                           wsf + WS_PBV, (int*)(wsf + WS_PBI));
  merge_kernel<<<(NPT + 255) / 256, 256, 0, stream>>>(wsf + WS_PBV, (int*)(wsf + WS_PBI),
                                                      (int*)(wsf + WS_IDX), out + OFF_CODES);
  gather_kernel<<<BDT / 256, 256, 0, stream>>>(z, cb, (int*)(wsf + WS_IDX),
                                               out + OFF_ZQ, out + OFF_EA,
                                               wsf + WS_COUNTS, wsf + WS_LOSS);
  cs_rand_kernel<<<KCB / 256, 256, 0, stream>>>(ema_cs, wsf + WS_COUNTS,
                                                wsf + WS_CS0, (uint32_t*)(wsf + WS_RAND),
                                                wsf + WS_NTOT);
  finalize_kernel<<<KD / 256, 256, 0, stream>>>(z, wsf + WS_CS0, (uint32_t*)(wsf + WS_RAND),
                                                wsf + WS_NTOT, wsf + WS_LOSS, out);
}

// Round 6
// 476.861 us; speedup vs baseline: 1.5954x; 1.4936x over previous
//
#include <hip/hip_runtime.h>
#include <stdint.h>

// Problem constants
#define KCB 4096
#define DIM 128
#define BSZ 8
#define TLEN 3000
#define NPT 24000            // BSZ*TLEN
#define KD (KCB*DIM)         // 524288
#define BDT (BSZ*DIM*TLEN)   // 3072000

// Output layout (floats, concatenated in reference return order)
#define OFF_ZQ    0
#define OFF_CODES 3072000
#define OFF_LOSS  3096000
#define OFF_CB    3096001
#define OFF_CS    3620289
#define OFF_EA    3624385

// Big scratch lives in d_out regions that are dead until later kernels:
//   zh/zl  -> [OFF_ZQ, OFF_ZQ+3072000)  (z_q written by gather AFTER mfma)
//   cbh/cbl-> [3096004, 3620292)        (new_codebook written by finalize LAST;
//                                        3-float spill into CS also rewritten)
#define OUT_ZH    0            // float offset; ushort[24000*128] = 1,536,000 floats
#define OUT_ZL    1536000
#define OUT_CBH   3096004      // 16B-aligned; ushort[4096*128] = 262,144 floats
#define OUT_CBL   3358148

// Workspace layout (float units) — total ~64,400 floats = 258 KB
#define WS_LOSS   0
#define WS_NTOT   1
#define WS_COUNTS 16                     // 4096
#define WS_Y2     (WS_COUNTS + 4096)     // 4096
#define WS_X2     (WS_Y2 + 4096)         // 24000
#define WS_CS0    (WS_X2 + 24000)        // 4096
#define WS_RAND   (WS_CS0 + 4096)        // uint32[4096]
#define WS_IDX    (WS_RAND + 4096)       // int32[24000]

#define EPS_CAND 2e-3f
#define CAND_MAX 8

typedef __attribute__((ext_vector_type(8))) short bf16x8;
typedef __attribute__((ext_vector_type(4))) float f32x4;
typedef __attribute__((ext_vector_type(4))) int i32x4;

__device__ __forceinline__ unsigned short f2bf(float f) {
  uint32_t u = __float_as_uint(f);
  uint32_t r = (u + 0x7FFFu + ((u >> 16) & 1u)) >> 16;   // RNE
  return (unsigned short)r;
}
__device__ __forceinline__ float bf2f(unsigned short h) {
  return __uint_as_float(((uint32_t)h) << 16);
}

// ---------------- threefry2x32-20 (JAX-compatible) ----------------
__device__ __forceinline__ void threefry2x32(uint32_t k0, uint32_t k1,
                                             uint32_t x0, uint32_t x1,
                                             uint32_t& o0, uint32_t& o1) {
  const uint32_t ks0 = k0, ks1 = k1, ks2 = k0 ^ k1 ^ 0x1BD11BDAu;
  const int r0[4] = {13, 15, 26, 6};
  const int r1[4] = {17, 29, 16, 24};
  x0 += ks0; x1 += ks1;
  #pragma unroll
  for (int i = 0; i < 5; ++i) {
    #pragma unroll
    for (int j = 0; j < 4; ++j) {
      int r = (i & 1) ? r1[j] : r0[j];
      x0 += x1;
      x1 = (x1 << r) | (x1 >> (32 - r));
      x1 ^= x0;
    }
    uint32_t ia = (uint32_t)((i + 1) % 3), ib = (uint32_t)((i + 2) % 3);
    uint32_t a = (ia == 0) ? ks0 : (ia == 1) ? ks1 : ks2;
    uint32_t b = (ib == 0) ? ks0 : (ib == 1) ? ks1 : ks2;
    x0 += a;
    x1 += b + (uint32_t)(i + 1);
  }
  o0 = x0; o1 = x1;
}

// numpy pairwise sum-of-squares, n=128: 8 accumulators, separately-rounded
// products, combine ((r0+r1)+(r2+r3))+((r4+r5)+(r6+r7)).
__device__ __forceinline__ float np_sumsq_128(const float* __restrict__ v) {
  float r[8];
  #pragma unroll
  for (int j = 0; j < 8; ++j) r[j] = __fmul_rn(v[j], v[j]);
  #pragma unroll
  for (int i = 8; i < DIM; i += 8) {
    #pragma unroll
    for (int j = 0; j < 8; ++j)
      r[j] = __fadd_rn(r[j], __fmul_rn(v[i + j], v[i + j]));
  }
  return __fadd_rn(__fadd_rn(__fadd_rn(r[0], r[1]), __fadd_rn(r[2], r[3])),
                   __fadd_rn(__fadd_rn(r[4], r[5]), __fadd_rn(r[6], r[7])));
}

// ---------------- prep_z: transpose z -> bf16 hi/lo rows + np-exact x2 -----
__global__ void prep_z_kernel(const float* __restrict__ z,
                              unsigned short* __restrict__ zh,
                              unsigned short* __restrict__ zl,
                              float* __restrict__ x2) {
  __shared__ float zt[64 * 132];
  const int tid = threadIdx.x;
  const int n0 = blockIdx.x * 64;
  {
    int nl = tid & 63, dd = tid >> 6;
    int n = n0 + nl;
    int b = n / TLEN, t = n - b * TLEN;
    const float* zbase = z + (size_t)b * (DIM * TLEN) + t;
    #pragma unroll
    for (int d = dd; d < DIM; d += 4) zt[nl * 132 + d] = zbase[(size_t)d * TLEN];
  }
  __syncthreads();
  if (tid < 64) x2[n0 + tid] = np_sumsq_128(zt + tid * 132);

  int r = tid >> 2, d0 = (tid & 3) * 32;
  const float* src = zt + r * 132 + d0;
  size_t base = (size_t)(n0 + r) * 128 + d0;
  #pragma unroll
  for (int c = 0; c < 4; ++c) {
    i32x4 wh, wl;
    #pragma unroll
    for (int q = 0; q < 4; ++q) {
      float f0 = src[c * 8 + q * 2], f1 = src[c * 8 + q * 2 + 1];
      unsigned short h0 = f2bf(f0), h1 = f2bf(f1);
      unsigned short l0 = f2bf(f0 - bf2f(h0)), l1 = f2bf(f1 - bf2f(h1));
      wh[q] = (int)((uint32_t)h0 | ((uint32_t)h1 << 16));
      wl[q] = (int)((uint32_t)l0 | ((uint32_t)l1 << 16));
    }
    *(i32x4*)(zh + base + c * 8) = wh;
    *(i32x4*)(zl + base + c * 8) = wl;
  }
}

// ---------------- prep_cb: cb -> bf16 hi/lo + np-exact y2 ----------------
__global__ void prep_cb_kernel(const float* __restrict__ cb,
                               unsigned short* __restrict__ cbh,
                               unsigned short* __restrict__ cbl,
                               float* __restrict__ y2) {
  int k = blockIdx.x * 256 + threadIdx.x;
  const float4* row4 = (const float4*)(cb + (size_t)k * DIM);
  float racc[8];
  #pragma unroll
  for (int j = 0; j < 8; ++j) racc[j] = 0.f;
  #pragma unroll 4
  for (int c2 = 0; c2 < 16; ++c2) {
    float4 a = row4[c2 * 2], b = row4[c2 * 2 + 1];
    float f[8] = {a.x, a.y, a.z, a.w, b.x, b.y, b.z, b.w};
    i32x4 wh, wl;
    #pragma unroll
    for (int q = 0; q < 4; ++q) {
      float f0 = f[q * 2], f1 = f[q * 2 + 1];
      unsigned short h0 = f2bf(f0), h1 = f2bf(f1);
      unsigned short l0 = f2bf(f0 - bf2f(h0)), l1 = f2bf(f1 - bf2f(h1));
      wh[q] = (int)((uint32_t)h0 | ((uint32_t)h1 << 16));
      wl[q] = (int)((uint32_t)l0 | ((uint32_t)l1 << 16));
    }
    *(i32x4*)(cbh + (size_t)k * DIM + c2 * 8) = wh;
    *(i32x4*)(cbl + (size_t)k * DIM + c2 * 8) = wl;
    #pragma unroll
    for (int j = 0; j < 8; ++j)
      racc[j] = __fadd_rn(racc[j], __fmul_rn(f[j], f[j]));
  }
  y2[k] = __fadd_rn(__fadd_rn(__fadd_rn(racc[0], racc[1]), __fadd_rn(racc[2], racc[3])),
                    __fadd_rn(__fadd_rn(racc[4], racc[5]), __fadd_rn(racc[6], racc[7])));
}

// ---------------- ea_init ----------------
__global__ void ea_init_kernel(const float* __restrict__ ema_ea, float* __restrict__ out_ea) {
  int i = blockIdx.x * 256 + threadIdx.x;
  out_ea[i] = 0.99f * ema_ea[i];
}

// ---------------- MFMA argmin: 750 blocks x 128 thr; 32n/block, full-K ------
// approx key(n,k) = y2[k] - 2*dot via 4-term bf16-split MFMA.
// Per-lane top-3 over INDIVIDUAL k distances (no frag compression) ->
// candidates within EPS -> exact np-fp32 rescore (ascending k, strict <).
__launch_bounds__(128)
__global__ void mfma_argmin_kernel(const unsigned short* __restrict__ zh,
                                   const unsigned short* __restrict__ zl,
                                   const unsigned short* __restrict__ cbh,
                                   const unsigned short* __restrict__ cbl,
                                   const float* __restrict__ y2g,
                                   const float* __restrict__ x2g,
                                   const float* __restrict__ z,
                                   const float* __restrict__ cb,
                                   int* __restrict__ idx_out,
                                   float* __restrict__ codes_out) {
  __shared__ alignas(16) unsigned short zh_t[32 * 128];   // swizzled [n][d]
  __shared__ alignas(16) unsigned short zl_t[32 * 128];
  __shared__ alignas(16) unsigned short ch_t[64 * 128];   // swizzled [k][d]
  __shared__ alignas(16) unsigned short cl_t[64 * 128];
  __shared__ alignas(16) float y2s[64];

  const int tid = threadIdx.x;
  const int wv = tid >> 6, lane = tid & 63;
  const int lg = lane >> 4, lc = lane & 15;
  const int n0 = blockIdx.x * 32;

  // stage z tiles once (chunk = 16B = 8 bf16; swizzle: chunk ^= row&7)
  {
    int r = tid >> 2, c0 = (tid & 3) * 4;
    const i32x4* gh = (const i32x4*)(zh + (size_t)(n0 + r) * 128);
    const i32x4* gl = (const i32x4*)(zl + (size_t)(n0 + r) * 128);
    #pragma unroll
    for (int c = 0; c < 4; ++c) {
      int cc = (c0 + c) ^ (r & 7);
      ((i32x4*)zh_t)[r * 16 + cc] = gh[c0 + c];
      ((i32x4*)zl_t)[r * 16 + cc] = gl[c0 + c];
    }
  }

  // codebook staging map: row = tid>>1 (0..63), 8 chunks starting (tid&1)*8
  const int srow = tid >> 1, sh = (tid & 1) * 8;
  i32x4 rbh[8], rbl[8];
  {
    const i32x4* gh = (const i32x4*)(cbh + (size_t)srow * 128);
    const i32x4* gl = (const i32x4*)(cbl + (size_t)srow * 128);
    #pragma unroll
    for (int c = 0; c < 8; ++c) { rbh[c] = gh[sh + c]; rbl[c] = gl[sh + c]; }
  }

  float t1v[2], t2v[2], t3v[2];
  int   t1i[2], t2i[2], t3i[2];
  #pragma unroll
  for (int ns = 0; ns < 2; ++ns) {
    t1v[ns] = t2v[ns] = t3v[ns] = 3.402823466e+38f;
    t1i[ns] = t2i[ns] = t3i[ns] = 0x7FFFFFFF;
  }

  for (int rd = 0; rd < KCB / 64; ++rd) {
    #pragma unroll
    for (int c = 0; c < 8; ++c) {
      int cc = (sh + c) ^ (srow & 7);
      ((i32x4*)ch_t)[srow * 16 + cc] = rbh[c];
      ((i32x4*)cl_t)[srow * 16 + cc] = rbl[c];
    }
    if (tid < 16) ((float4*)y2s)[tid] = ((const float4*)(y2g + rd * 64))[tid];
    __syncthreads();

    if (rd + 1 < KCB / 64) {
      const i32x4* gh = (const i32x4*)(cbh + (size_t)((rd + 1) * 64 + srow) * 128);
      const i32x4* gl = (const i32x4*)(cbl + (size_t)((rd + 1) * 64 + srow) * 128);
      #pragma unroll
      for (int c = 0; c < 8; ++c) { rbh[c] = gh[sh + c]; rbl[c] = gl[sh + c]; }
    }

    f32x4 acc[2][2];   // [nsub][ksub]
    #pragma unroll
    for (int ns = 0; ns < 2; ++ns)
      #pragma unroll
      for (int ks = 0; ks < 2; ++ks) acc[ns][ks] = 0.f;

    #pragma unroll
    for (int ds = 0; ds < 4; ++ds) {
      bf16x8 ah[2], al[2], bh[2], bl[2];
      #pragma unroll
      for (int ks = 0; ks < 2; ++ks) {
        int row = wv * 32 + ks * 16 + lc;
        int cc = (ds * 4 + lg) ^ (row & 7);
        ah[ks] = *(const bf16x8*)&ch_t[row * 128 + cc * 8];
        al[ks] = *(const bf16x8*)&cl_t[row * 128 + cc * 8];
      }
      #pragma unroll
      for (int ns = 0; ns < 2; ++ns) {
        int row = ns * 16 + lc;
        int cc = (ds * 4 + lg) ^ (row & 7);
        bh[ns] = *(const bf16x8*)&zh_t[row * 128 + cc * 8];
        bl[ns] = *(const bf16x8*)&zl_t[row * 128 + cc * 8];
      }
      #pragma unroll
      for (int ns = 0; ns < 2; ++ns)
        #pragma unroll
        for (int ks = 0; ks < 2; ++ks) {
          acc[ns][ks] = __builtin_amdgcn_mfma_f32_16x16x32_bf16(ah[ks], bh[ns], acc[ns][ks], 0, 0, 0);
          acc[ns][ks] = __builtin_amdgcn_mfma_f32_16x16x32_bf16(ah[ks], bl[ns], acc[ns][ks], 0, 0, 0);
          acc[ns][ks] = __builtin_amdgcn_mfma_f32_16x16x32_bf16(al[ks], bh[ns], acc[ns][ks], 0, 0, 0);
          acc[ns][ks] = __builtin_amdgcn_mfma_f32_16x16x32_bf16(al[ks], bl[ns], acc[ns][ks], 0, 0, 0);
        }
    }

    // distances + per-lane top-3 over INDIVIDUAL k (no frag compression)
    #pragma unroll
    for (int ks = 0; ks < 2; ++ks) {
      int klocal = wv * 32 + ks * 16 + lg * 4;
      float4 y4 = *(const float4*)&y2s[klocal];
      int kbase = rd * 64 + klocal;
      #pragma unroll
      for (int ns = 0; ns < 2; ++ns) {
        float dv[4];
        dv[0] = fmaf(-2.f, acc[ns][ks][0], y4.x);
        dv[1] = fmaf(-2.f, acc[ns][ks][1], y4.y);
        dv[2] = fmaf(-2.f, acc[ns][ks][2], y4.z);
        dv[3] = fmaf(-2.f, acc[ns][ks][3], y4.w);
        #pragma unroll
        for (int q = 0; q < 4; ++q) {
          float v = dv[q];
          int kidx = kbase + q;
          bool c1 = v < t1v[ns], c2 = v < t2v[ns], c3 = v < t3v[ns];
          float n3v = c2 ? t2v[ns] : (c3 ? v : t3v[ns]);
          int   n3i = c2 ? t2i[ns] : (c3 ? kidx : t3i[ns]);
          float n2v = c1 ? t1v[ns] : (c2 ? v : t2v[ns]);
          int   n2i = c1 ? t1i[ns] : (c2 ? kidx : t2i[ns]);
          t1v[ns] = c1 ? v : t1v[ns]; t1i[ns] = c1 ? kidx : t1i[ns];
          t2v[ns] = n2v; t2i[ns] = n2i;
          t3v[ns] = n3v; t3i[ns] = n3i;
        }
      }
    }
    __syncthreads();
  }

  // ---- tail: merge 8 per-lane lists per row, candidates, exact rescore
  float* tv = (float*)ch_t;   // 32n * 8 lists * 3
  int*   ti = (int*)cl_t;
  #pragma unroll
  for (int ns = 0; ns < 2; ++ns) {
    int nl = ns * 16 + lc;
    int base = (nl * 8 + wv * 4 + lg) * 3;
    tv[base + 0] = t1v[ns]; ti[base + 0] = t1i[ns];
    tv[base + 1] = t2v[ns]; ti[base + 1] = t2i[ns];
    tv[base + 2] = t3v[ns]; ti[base + 2] = t3i[ns];
  }
  __syncthreads();

  if (tid < 32) {
    int n = n0 + tid;
    float bv = 3.402823466e+38f; int bi = 0x7FFFFFFF;
    for (int e = 0; e < 24; ++e) {
      float v = tv[tid * 24 + e]; int i2 = ti[tid * 24 + e];
      if (v < bv || (v == bv && i2 < bi)) { bv = v; bi = i2; }
    }
    int ci[CAND_MAX]; int cnt = 0;
    float lim = bv + EPS_CAND;
    for (int e = 0; e < 24; ++e) {
      float v = tv[tid * 24 + e];
      if (v <= lim && cnt < CAND_MAX) {
        int x = ti[tid * 24 + e];
        // dedup (same k can appear in multiple lists? no—each k in one lane;
        // but keep sorted-ascending insert)
        int p = cnt++;
        while (p > 0 && ci[p - 1] > x) { ci[p] = ci[p - 1]; --p; }
        ci[p] = x;
      }
    }
    int kbest = ci[0];
    if (cnt > 1) {
      int b = n / TLEN, t = n - b * TLEN;
      const float* zr = z + (size_t)b * (DIM * TLEN) + t;
      float bestv = 0.f;
      for (int c = 0; c < cnt; ++c) {
        int k = ci[c];
        const float* cr = cb + (size_t)k * DIM;
        float dot = 0.f;
        for (int d = 0; d < DIM; ++d)
          dot = __fmaf_rn(zr[(size_t)d * TLEN], cr[d], dot);
        float tt = __fadd_rn(x2g[n], y2g[k]);
        float dist = __fsub_rn(tt, __fmul_rn(2.0f, dot));
        if (c == 0 || dist < bestv) { bestv = dist; kbest = k; }
      }
    }
    idx_out[n] = kbest;
    codes_out[n] = (float)kbest;
  }
}

// ---------------- gather: z_q, commit-loss, segment sums ----------------
__global__ void gather_kernel(const float* __restrict__ z, const float* __restrict__ cb,
                              const int* __restrict__ idx,
                              float* __restrict__ zq_out, float* __restrict__ ea_out,
                              float* __restrict__ counts, float* __restrict__ loss_ws) {
  int i = blockIdx.x * 256 + threadIdx.x;   // [B][D][T]
  int t = i % TLEN;
  int bd = i / TLEN;
  int d = bd & (DIM - 1);
  int b = bd >> 7;
  int n = b * TLEN + t;
  int k = idx[n];
  float zv = z[i];
  float q = cb[(size_t)k * DIM + d];
  zq_out[i] = q;
  float diff = zv - q;
  float sq = diff * diff;
  #pragma unroll
  for (int m = 1; m <= 32; m <<= 1) sq += __shfl_xor(sq, m);
  __shared__ float ps[4];
  if ((threadIdx.x & 63) == 0) ps[threadIdx.x >> 6] = sq;
  __syncthreads();
  if (threadIdx.x == 0) atomicAdd(loss_ws, ps[0] + ps[1] + ps[2] + ps[3]);
  atomicAdd(ea_out + (size_t)k * DIM + d, 0.01f * zv);
  if (d == 0) atomicAdd(counts + k, 1.0f);
}

// ---------------- cs_rand ----------------
__global__ void cs_rand_kernel(const float* __restrict__ ema_cs, const float* __restrict__ counts,
                               float* __restrict__ cs0, uint32_t* __restrict__ rnd,
                               float* __restrict__ ntot) {
  int k = blockIdx.x * 256 + threadIdx.x;
  float v = 0.99f * ema_cs[k] + 0.01f * counts[k];
  cs0[k] = v;

  uint32_t o0, o1;
  threefry2x32(0u, 42u, 0u, (uint32_t)k, o0, o1);
  uint32_t bits = o0 ^ o1;
  uint32_t hi = bits >> 16, lo = bits & 0xffffu;
  const uint32_t span = 24000u, mult = 23296u;  // 2^32 % 24000
  uint32_t off = ((hi % span) * mult + (lo % span)) % span;
  rnd[k] = off;

  float s = v;
  #pragma unroll
  for (int m = 1; m <= 32; m <<= 1) s += __shfl_xor(s, m);
  __shared__ float ps[4];
  if ((threadIdx.x & 63) == 0) ps[threadIdx.x >> 6] = s;
  __syncthreads();
  if (threadIdx.x == 0) atomicAdd(ntot, ps[0] + ps[1] + ps[2] + ps[3]);
}

// ---------------- finalize ----------------
__global__ void finalize_kernel(const float* __restrict__ z, const float* __restrict__ cs0_ws,
                                const uint32_t* __restrict__ rnd,
                                const float* __restrict__ ntot_ws, const float* __restrict__ loss_ws,
                                float* __restrict__ out) {
  int i = blockIdx.x * 256 + threadIdx.x;   // i < KD
  int k = i >> 7, d = i & (DIM - 1);
  float cs0 = cs0_ws[k];
  float ntot = *ntot_ws;
  float* ea = out + OFF_EA;
  float ea0 = ea[i];
  float csz = (cs0 + 1e-5f) / (ntot + (float)KCB * 1e-5f) * ntot;
  float embed = ea0 / fmaxf(csz, 1e-12f);
  bool dead = cs0 < 2.0f;
  uint32_t rn = rnd[k];
  int bb = (int)(rn / TLEN), tt = (int)(rn % TLEN);
  float sampled = z[(size_t)bb * (DIM * TLEN) + (size_t)d * TLEN + tt];
  out[OFF_CB + i] = dead ? sampled : embed;
  ea[i] = dead ? sampled : ea0;
  if (d == 0) out[OFF_CS + k] = dead ? 1.0f : cs0;
  if (i == 0) out[OFF_LOSS] = (*loss_ws) * (1.0f / (float)BDT);
}

extern "C" void kernel_launch(void* const* d_in, const int* in_sizes, int n_in,
                              void* d_out, int out_size, void* d_ws, size_t ws_size,
                              hipStream_t stream) {
  const float* z      = (const float*)d_in[0];
  const float* cb     = (const float*)d_in[1];
  const float* ema_cs = (const float*)d_in[2];
  const float* ema_ea = (const float*)d_in[3];
  float* out = (float*)d_out;
  float* wsf = (float*)d_ws;

  unsigned short* zh  = (unsigned short*)(out + OUT_ZH);
  unsigned short* zl  = (unsigned short*)(out + OUT_ZL);
  unsigned short* cbh = (unsigned short*)(out + OUT_CBH);
  unsigned short* cbl = (unsigned short*)(out + OUT_CBL);

  hipMemsetAsync(d_ws, 0, (size_t)(16 + 4096) * sizeof(float), stream);

  prep_cb_kernel<<<KCB / 256, 256, 0, stream>>>(cb, cbh, cbl, wsf + WS_Y2);
  prep_z_kernel<<<NPT / 64, 256, 0, stream>>>(z, zh, zl, wsf + WS_X2);
  ea_init_kernel<<<KD / 256, 256, 0, stream>>>(ema_ea, out + OFF_EA);

  mfma_argmin_kernel<<<NPT / 32, 128, 0, stream>>>(zh, zl, cbh, cbl,
                                                   wsf + WS_Y2, wsf + WS_X2,
                                                   z, cb,
                                                   (int*)(wsf + WS_IDX), out + OFF_CODES);

  gather_kernel<<<BDT / 256, 256, 0, stream>>>(z, cb, (int*)(wsf + WS_IDX),
                                               out + OFF_ZQ, out + OFF_EA,
                                               wsf + WS_COUNTS, wsf + WS_LOSS);
  cs_rand_kernel<<<KCB / 256, 256, 0, stream>>>(ema_cs, wsf + WS_COUNTS,
                                                wsf + WS_CS0, (uint32_t*)(wsf + WS_RAND),
                                                wsf + WS_NTOT);
  finalize_kernel<<<KD / 256, 256, 0, stream>>>(z, wsf + WS_CS0, (uint32_t*)(wsf + WS_RAND),
                                                wsf + WS_NTOT, wsf + WS_LOSS, out);
}

// Round 7
// 468.259 us; speedup vs baseline: 1.6247x; 1.0184x over previous
//
#include <hip/hip_runtime.h>
#include <stdint.h>

// Problem constants
#define KCB 4096
#define DIM 128
#define BSZ 8
#define TLEN 3000
#define NPT 24000            // BSZ*TLEN
#define KD (KCB*DIM)         // 524288
#define BDT (BSZ*DIM*TLEN)   // 3072000

// Output layout (floats, concatenated in reference return order)
#define OFF_ZQ    0
#define OFF_CODES 3072000
#define OFF_LOSS  3096000
#define OFF_CB    3096001
#define OFF_CS    3620289
#define OFF_EA    3624385

// Big scratch lives in d_out regions that are dead until later kernels:
//   zh/zl  -> [OFF_ZQ, OFF_ZQ+3072000)  (z_q written by gather AFTER mfma)
//   cbh/cbl-> [3096004, 3620292)        (new_codebook written by finalize LAST;
//                                        3-float spill into CS also rewritten)
#define OUT_ZH    0            // float offset; ushort[24000*128] = 1,536,000 floats
#define OUT_ZL    1536000
#define OUT_CBH   3096004      // 16B-aligned; ushort[4096*128] = 262,144 floats
#define OUT_CBL   3358148

// Workspace layout (float units) — total ~64,400 floats = 258 KB
#define WS_LOSS   0
#define WS_NTOT   1
#define WS_COUNTS 16                     // 4096
#define WS_Y2     (WS_COUNTS + 4096)     // 4096
#define WS_X2     (WS_Y2 + 4096)         // 24000
#define WS_CS0    (WS_X2 + 24000)        // 4096
#define WS_RAND   (WS_CS0 + 4096)        // uint32[4096]
#define WS_IDX    (WS_RAND + 4096)       // int32[24000]

#define EPS_CAND 2e-3f
#define CAND_MAX 8

typedef __attribute__((ext_vector_type(8))) short bf16x8;
typedef __attribute__((ext_vector_type(4))) float f32x4;
typedef __attribute__((ext_vector_type(4))) int i32x4;

__device__ __forceinline__ unsigned short f2bf(float f) {
  uint32_t u = __float_as_uint(f);
  uint32_t r = (u + 0x7FFFu + ((u >> 16) & 1u)) >> 16;   // RNE
  return (unsigned short)r;
}
__device__ __forceinline__ float bf2f(unsigned short h) {
  return __uint_as_float(((uint32_t)h) << 16);
}

// ---------------- threefry2x32-20 (JAX-compatible) ----------------
__device__ __forceinline__ void threefry2x32(uint32_t k0, uint32_t k1,
                                             uint32_t x0, uint32_t x1,
                                             uint32_t& o0, uint32_t& o1) {
  const uint32_t ks0 = k0, ks1 = k1, ks2 = k0 ^ k1 ^ 0x1BD11BDAu;
  const int r0[4] = {13, 15, 26, 6};
  const int r1[4] = {17, 29, 16, 24};
  x0 += ks0; x1 += ks1;
  #pragma unroll
  for (int i = 0; i < 5; ++i) {
    #pragma unroll
    for (int j = 0; j < 4; ++j) {
      int r = (i & 1) ? r1[j] : r0[j];
      x0 += x1;
      x1 = (x1 << r) | (x1 >> (32 - r));
      x1 ^= x0;
    }
    uint32_t ia = (uint32_t)((i + 1) % 3), ib = (uint32_t)((i + 2) % 3);
    uint32_t a = (ia == 0) ? ks0 : (ia == 1) ? ks1 : ks2;
    uint32_t b = (ib == 0) ? ks0 : (ib == 1) ? ks1 : ks2;
    x0 += a;
    x1 += b + (uint32_t)(i + 1);
  }
  o0 = x0; o1 = x1;
}

// numpy pairwise sum-of-squares, n=128: 8 accumulators, separately-rounded
// products, combine ((r0+r1)+(r2+r3))+((r4+r5)+(r6+r7)).
__device__ __forceinline__ float np_sumsq_128(const float* __restrict__ v) {
  float r[8];
  #pragma unroll
  for (int j = 0; j < 8; ++j) r[j] = __fmul_rn(v[j], v[j]);
  #pragma unroll
  for (int i = 8; i < DIM; i += 8) {
    #pragma unroll
    for (int j = 0; j < 8; ++j)
      r[j] = __fadd_rn(r[j], __fmul_rn(v[i + j], v[i + j]));
  }
  return __fadd_rn(__fadd_rn(__fadd_rn(r[0], r[1]), __fadd_rn(r[2], r[3])),
                   __fadd_rn(__fadd_rn(r[4], r[5]), __fadd_rn(r[6], r[7])));
}

// ---------------- prep_z: transpose z -> bf16 hi/lo rows + np-exact x2 -----
__global__ void prep_z_kernel(const float* __restrict__ z,
                              unsigned short* __restrict__ zh,
                              unsigned short* __restrict__ zl,
                              float* __restrict__ x2) {
  __shared__ float zt[64 * 132];
  const int tid = threadIdx.x;
  const int n0 = blockIdx.x * 64;
  {
    int nl = tid & 63, dd = tid >> 6;
    int n = n0 + nl;
    int b = n / TLEN, t = n - b * TLEN;
    const float* zbase = z + (size_t)b * (DIM * TLEN) + t;
    #pragma unroll
    for (int d = dd; d < DIM; d += 4) zt[nl * 132 + d] = zbase[(size_t)d * TLEN];
  }
  __syncthreads();
  if (tid < 64) x2[n0 + tid] = np_sumsq_128(zt + tid * 132);

  int r = tid >> 2, d0 = (tid & 3) * 32;
  const float* src = zt + r * 132 + d0;
  size_t base = (size_t)(n0 + r) * 128 + d0;
  #pragma unroll
  for (int c = 0; c < 4; ++c) {
    i32x4 wh, wl;
    #pragma unroll
    for (int q = 0; q < 4; ++q) {
      float f0 = src[c * 8 + q * 2], f1 = src[c * 8 + q * 2 + 1];
      unsigned short h0 = f2bf(f0), h1 = f2bf(f1);
      unsigned short l0 = f2bf(f0 - bf2f(h0)), l1 = f2bf(f1 - bf2f(h1));
      wh[q] = (int)((uint32_t)h0 | ((uint32_t)h1 << 16));
      wl[q] = (int)((uint32_t)l0 | ((uint32_t)l1 << 16));
    }
    *(i32x4*)(zh + base + c * 8) = wh;
    *(i32x4*)(zl + base + c * 8) = wl;
  }
}

// ---------------- prep_cb: cb -> bf16 hi/lo + np-exact y2 ----------------
__global__ void prep_cb_kernel(const float* __restrict__ cb,
                               unsigned short* __restrict__ cbh,
                               unsigned short* __restrict__ cbl,
                               float* __restrict__ y2) {
  int k = blockIdx.x * 256 + threadIdx.x;
  const float4* row4 = (const float4*)(cb + (size_t)k * DIM);
  float racc[8];
  #pragma unroll
  for (int j = 0; j < 8; ++j) racc[j] = 0.f;
  #pragma unroll 4
  for (int c2 = 0; c2 < 16; ++c2) {
    float4 a = row4[c2 * 2], b = row4[c2 * 2 + 1];
    float f[8] = {a.x, a.y, a.z, a.w, b.x, b.y, b.z, b.w};
    i32x4 wh, wl;
    #pragma unroll
    for (int q = 0; q < 4; ++q) {
      float f0 = f[q * 2], f1 = f[q * 2 + 1];
      unsigned short h0 = f2bf(f0), h1 = f2bf(f1);
      unsigned short l0 = f2bf(f0 - bf2f(h0)), l1 = f2bf(f1 - bf2f(h1));
      wh[q] = (int)((uint32_t)h0 | ((uint32_t)h1 << 16));
      wl[q] = (int)((uint32_t)l0 | ((uint32_t)l1 << 16));
    }
    *(i32x4*)(cbh + (size_t)k * DIM + c2 * 8) = wh;
    *(i32x4*)(cbl + (size_t)k * DIM + c2 * 8) = wl;
    #pragma unroll
    for (int j = 0; j < 8; ++j)
      racc[j] = __fadd_rn(racc[j], __fmul_rn(f[j], f[j]));
  }
  y2[k] = __fadd_rn(__fadd_rn(__fadd_rn(racc[0], racc[1]), __fadd_rn(racc[2], racc[3])),
                    __fadd_rn(__fadd_rn(racc[4], racc[5]), __fadd_rn(racc[6], racc[7])));
}

// ---------------- ea_init ----------------
__global__ void ea_init_kernel(const float* __restrict__ ema_ea, float* __restrict__ out_ea) {
  int i = blockIdx.x * 256 + threadIdx.x;
  out_ea[i] = 0.99f * ema_ea[i];
}

// ---------------- MFMA argmin: 750 blocks x 128 thr; 32n/block, full-K ------
// approx key(n,k) = y2[k] - 2*dot via 4-term bf16-split MFMA.
// Per-lane top-3 over INDIVIDUAL k distances (no frag compression) ->
// candidates within EPS -> exact np-fp32 rescore (ascending k, strict <).
__launch_bounds__(128)
__global__ void mfma_argmin_kernel(const unsigned short* __restrict__ zh,
                                   const unsigned short* __restrict__ zl,
                                   const unsigned short* __restrict__ cbh,
                                   const unsigned short* __restrict__ cbl,
                                   const float* __restrict__ y2g,
                                   const float* __restrict__ x2g,
                                   const float* __restrict__ z,
                                   const float* __restrict__ cb,
                                   int* __restrict__ idx_out,
                                   float* __restrict__ codes_out) {
  __shared__ alignas(16) unsigned short zh_t[32 * 128];   // swizzled [n][d]
  __shared__ alignas(16) unsigned short zl_t[32 * 128];
  __shared__ alignas(16) unsigned short ch_t[64 * 128];   // swizzled [k][d]
  __shared__ alignas(16) unsigned short cl_t[64 * 128];
  __shared__ alignas(16) float y2s[64];

  const int tid = threadIdx.x;
  const int wv = tid >> 6, lane = tid & 63;
  const int lg = lane >> 4, lc = lane & 15;
  const int n0 = blockIdx.x * 32;

  // stage z tiles once (chunk = 16B = 8 bf16; swizzle: chunk ^= row&7)
  {
    int r = tid >> 2, c0 = (tid & 3) * 4;
    const i32x4* gh = (const i32x4*)(zh + (size_t)(n0 + r) * 128);
    const i32x4* gl = (const i32x4*)(zl + (size_t)(n0 + r) * 128);
    #pragma unroll
    for (int c = 0; c < 4; ++c) {
      int cc = (c0 + c) ^ (r & 7);
      ((i32x4*)zh_t)[r * 16 + cc] = gh[c0 + c];
      ((i32x4*)zl_t)[r * 16 + cc] = gl[c0 + c];
    }
  }

  // codebook staging map: row = tid>>1 (0..63), 8 chunks starting (tid&1)*8
  const int srow = tid >> 1, sh = (tid & 1) * 8;
  i32x4 rbh[8], rbl[8];
  {
    const i32x4* gh = (const i32x4*)(cbh + (size_t)srow * 128);
    const i32x4* gl = (const i32x4*)(cbl + (size_t)srow * 128);
    #pragma unroll
    for (int c = 0; c < 8; ++c) { rbh[c] = gh[sh + c]; rbl[c] = gl[sh + c]; }
  }

  float t1v[2], t2v[2], t3v[2];
  int   t1i[2], t2i[2], t3i[2];
  #pragma unroll
  for (int ns = 0; ns < 2; ++ns) {
    t1v[ns] = t2v[ns] = t3v[ns] = 3.402823466e+38f;
    t1i[ns] = t2i[ns] = t3i[ns] = 0x7FFFFFFF;
  }

  for (int rd = 0; rd < KCB / 64; ++rd) {
    #pragma unroll
    for (int c = 0; c < 8; ++c) {
      int cc = (sh + c) ^ (srow & 7);
      ((i32x4*)ch_t)[srow * 16 + cc] = rbh[c];
      ((i32x4*)cl_t)[srow * 16 + cc] = rbl[c];
    }
    if (tid < 16) ((float4*)y2s)[tid] = ((const float4*)(y2g + rd * 64))[tid];
    __syncthreads();

    if (rd + 1 < KCB / 64) {
      const i32x4* gh = (const i32x4*)(cbh + (size_t)((rd + 1) * 64 + srow) * 128);
      const i32x4* gl = (const i32x4*)(cbl + (size_t)((rd + 1) * 64 + srow) * 128);
      #pragma unroll
      for (int c = 0; c < 8; ++c) { rbh[c] = gh[sh + c]; rbl[c] = gl[sh + c]; }
    }

    f32x4 acc[2][2];   // [nsub][ksub]
    #pragma unroll
    for (int ns = 0; ns < 2; ++ns)
      #pragma unroll
      for (int ks = 0; ks < 2; ++ks) acc[ns][ks] = 0.f;

    #pragma unroll
    for (int ds = 0; ds < 4; ++ds) {
      bf16x8 ah[2], al[2], bh[2], bl[2];
      #pragma unroll
      for (int ks = 0; ks < 2; ++ks) {
        int row = wv * 32 + ks * 16 + lc;
        int cc = (ds * 4 + lg) ^ (row & 7);
        ah[ks] = *(const bf16x8*)&ch_t[row * 128 + cc * 8];
        al[ks] = *(const bf16x8*)&cl_t[row * 128 + cc * 8];
      }
      #pragma unroll
      for (int ns = 0; ns < 2; ++ns) {
        int row = ns * 16 + lc;
        int cc = (ds * 4 + lg) ^ (row & 7);
        bh[ns] = *(const bf16x8*)&zh_t[row * 128 + cc * 8];
        bl[ns] = *(const bf16x8*)&zl_t[row * 128 + cc * 8];
      }
      #pragma unroll
      for (int ns = 0; ns < 2; ++ns)
        #pragma unroll
        for (int ks = 0; ks < 2; ++ks) {
          acc[ns][ks] = __builtin_amdgcn_mfma_f32_16x16x32_bf16(ah[ks], bh[ns], acc[ns][ks], 0, 0, 0);
          acc[ns][ks] = __builtin_amdgcn_mfma_f32_16x16x32_bf16(ah[ks], bl[ns], acc[ns][ks], 0, 0, 0);
          acc[ns][ks] = __builtin_amdgcn_mfma_f32_16x16x32_bf16(al[ks], bh[ns], acc[ns][ks], 0, 0, 0);
          acc[ns][ks] = __builtin_amdgcn_mfma_f32_16x16x32_bf16(al[ks], bl[ns], acc[ns][ks], 0, 0, 0);
        }
    }

    // distances + per-lane top-3 over INDIVIDUAL k (no frag compression)
    #pragma unroll
    for (int ks = 0; ks < 2; ++ks) {
      int klocal = wv * 32 + ks * 16 + lg * 4;
      float4 y4 = *(const float4*)&y2s[klocal];
      int kbase = rd * 64 + klocal;
      #pragma unroll
      for (int ns = 0; ns < 2; ++ns) {
        float dv[4];
        dv[0] = fmaf(-2.f, acc[ns][ks][0], y4.x);
        dv[1] = fmaf(-2.f, acc[ns][ks][1], y4.y);
        dv[2] = fmaf(-2.f, acc[ns][ks][2], y4.z);
        dv[3] = fmaf(-2.f, acc[ns][ks][3], y4.w);
        #pragma unroll
        for (int q = 0; q < 4; ++q) {
          float v = dv[q];
          int kidx = kbase + q;
          bool c1 = v < t1v[ns], c2 = v < t2v[ns], c3 = v < t3v[ns];
          float n3v = c2 ? t2v[ns] : (c3 ? v : t3v[ns]);
          int   n3i = c2 ? t2i[ns] : (c3 ? kidx : t3i[ns]);
          float n2v = c1 ? t1v[ns] : (c2 ? v : t2v[ns]);
          int   n2i = c1 ? t1i[ns] : (c2 ? kidx : t2i[ns]);
          t1v[ns] = c1 ? v : t1v[ns]; t1i[ns] = c1 ? kidx : t1i[ns];
          t2v[ns] = n2v; t2i[ns] = n2i;
          t3v[ns] = n3v; t3i[ns] = n3i;
        }
      }
    }
    __syncthreads();
  }

  // ---- tail: merge 8 per-lane lists per row, candidates, exact rescore
  float* tv = (float*)ch_t;   // 32n * 8 lists * 3
  int*   ti = (int*)cl_t;
  #pragma unroll
  for (int ns = 0; ns < 2; ++ns) {
    int nl = ns * 16 + lc;
    int base = (nl * 8 + wv * 4 + lg) * 3;
    tv[base + 0] = t1v[ns]; ti[base + 0] = t1i[ns];
    tv[base + 1] = t2v[ns]; ti[base + 1] = t2i[ns];
    tv[base + 2] = t3v[ns]; ti[base + 2] = t3i[ns];
  }
  __syncthreads();

  if (tid < 32) {
    int n = n0 + tid;
    float bv = 3.402823466e+38f; int bi = 0x7FFFFFFF;
    for (int e = 0; e < 24; ++e) {
      float v = tv[tid * 24 + e]; int i2 = ti[tid * 24 + e];
      if (v < bv || (v == bv && i2 < bi)) { bv = v; bi = i2; }
    }
    int ci[CAND_MAX]; int cnt = 0;
    float lim = bv + EPS_CAND;
    for (int e = 0; e < 24; ++e) {
      float v = tv[tid * 24 + e];
      if (v <= lim && cnt < CAND_MAX) {
        int x = ti[tid * 24 + e];
        // dedup (same k can appear in multiple lists? no—each k in one lane;
        // but keep sorted-ascending insert)
        int p = cnt++;
        while (p > 0 && ci[p - 1] > x) { ci[p] = ci[p - 1]; --p; }
        ci[p] = x;
      }
    }
    int kbest = ci[0];
    if (cnt > 1) {
      int b = n / TLEN, t = n - b * TLEN;
      const float* zr = z + (size_t)b * (DIM * TLEN) + t;
      float bestv = 0.f;
      for (int c = 0; c < cnt; ++c) {
        int k = ci[c];
        const float* cr = cb + (size_t)k * DIM;
        float dot = 0.f;
        for (int d = 0; d < DIM; ++d)
          dot = __fmaf_rn(zr[(size_t)d * TLEN], cr[d], dot);
        float tt = __fadd_rn(x2g[n], y2g[k]);
        float dist = __fsub_rn(tt, __fmul_rn(2.0f, dot));
        if (c == 0 || dist < bestv) { bestv = dist; kbest = k; }
      }
    }
    idx_out[n] = kbest;
    codes_out[n] = (float)kbest;
  }
}

// ---------------- gather: z_q, commit-loss, segment sums ----------------
__global__ void gather_kernel(const float* __restrict__ z, const float* __restrict__ cb,
                              const int* __restrict__ idx,
                              float* __restrict__ zq_out, float* __restrict__ ea_out,
                              float* __restrict__ counts, float* __restrict__ loss_ws) {
  int i = blockIdx.x * 256 + threadIdx.x;   // [B][D][T]
  int t = i % TLEN;
  int bd = i / TLEN;
  int d = bd & (DIM - 1);
  int b = bd >> 7;
  int n = b * TLEN + t;
  int k = idx[n];
  float zv = z[i];
  float q = cb[(size_t)k * DIM + d];
  zq_out[i] = q;
  float diff = zv - q;
  float sq = diff * diff;
  #pragma unroll
  for (int m = 1; m <= 32; m <<= 1) sq += __shfl_xor(sq, m);
  __shared__ float ps[4];
  if ((threadIdx.x & 63) == 0) ps[threadIdx.x >> 6] = sq;
  __syncthreads();
  if (threadIdx.x == 0) atomicAdd(loss_ws, ps[0] + ps[1] + ps[2] + ps[3]);
  atomicAdd(ea_out + (size_t)k * DIM + d, 0.01f * zv);
  if (d == 0) atomicAdd(counts + k, 1.0f);
}

// ---------------- cs_rand ----------------
__global__ void cs_rand_kernel(const float* __restrict__ ema_cs, const float* __restrict__ counts,
                               float* __restrict__ cs0, uint32_t* __restrict__ rnd,
                               float* __restrict__ ntot) {
  int k = blockIdx.x * 256 + threadIdx.x;
  float v = 0.99f * ema_cs[k] + 0.01f * counts[k];
  cs0[k] = v;

  uint32_t o0, o1;
  threefry2x32(0u, 42u, 0u, (uint32_t)k, o0, o1);
  uint32_t bits = o0 ^ o1;
  uint32_t hi = bits >> 16, lo = bits & 0xffffu;
  const uint32_t span = 24000u, mult = 23296u;  // 2^32 % 24000
  uint32_t off = ((hi % span) * mult + (lo % span)) % span;
  rnd[k] = off;

  float s = v;
  #pragma unroll
  for (int m = 1; m <= 32; m <<= 1) s += __shfl_xor(s, m);
  __shared__ float ps[4];
  if ((threadIdx.x & 63) == 0) ps[threadIdx.x >> 6] = s;
  __syncthreads();
  if (threadIdx.x == 0) atomicAdd(ntot, ps[0] + ps[1] + ps[2] + ps[3]);
}

// ---------------- finalize ----------------
__global__ void finalize_kernel(const float* __restrict__ z, const float* __restrict__ cs0_ws,
                                const uint32_t* __restrict__ rnd,
                                const float* __restrict__ ntot_ws, const float* __restrict__ loss_ws,
                                float* __restrict__ out) {
  int i = blockIdx.x * 256 + threadIdx.x;   // i < KD
  int k = i >> 7, d = i & (DIM - 1);
  float cs0 = cs0_ws[k];
  float ntot = *ntot_ws;
  float* ea = out + OFF_EA;
  float ea0 = ea[i];
  float csz = (cs0 + 1e-5f) / (ntot + (float)KCB * 1e-5f) * ntot;
  float embed = ea0 / fmaxf(csz, 1e-12f);
  bool dead = cs0 < 2.0f;
  uint32_t rn = rnd[k];
  int bb = (int)(rn / TLEN), tt = (int)(rn % TLEN);
  float sampled = z[(size_t)bb * (DIM * TLEN) + (size_t)d * TLEN + tt];
  out[OFF_CB + i] = dead ? sampled : embed;
  ea[i] = dead ? sampled : ea0;
  if (d == 0) out[OFF_CS + k] = dead ? 1.0f : cs0;
  if (i == 0) out[OFF_LOSS] = (*loss_ws) * (1.0f / (float)BDT);
}

extern "C" void kernel_launch(void* const* d_in, const int* in_sizes, int n_in,
                              void* d_out, int out_size, void* d_ws, size_t ws_size,
                              hipStream_t stream) {
  const float* z      = (const float*)d_in[0];
  const float* cb     = (const float*)d_in[1];
  const float* ema_cs = (const float*)d_in[2];
  const float* ema_ea = (const float*)d_in[3];
  float* out = (float*)d_out;
  float* wsf = (float*)d_ws;

  unsigned short* zh  = (unsigned short*)(out + OUT_ZH);
  unsigned short* zl  = (unsigned short*)(out + OUT_ZL);
  unsigned short* cbh = (unsigned short*)(out + OUT_CBH);
  unsigned short* cbl = (unsigned short*)(out + OUT_CBL);

  hipMemsetAsync(d_ws, 0, (size_t)(16 + 4096) * sizeof(float), stream);

  prep_cb_kernel<<<KCB / 256, 256, 0, stream>>>(cb, cbh, cbl, wsf + WS_Y2);
  prep_z_kernel<<<NPT / 64, 256, 0, stream>>>(z, zh, zl, wsf + WS_X2);
  ea_init_kernel<<<KD / 256, 256, 0, stream>>>(ema_ea, out + OFF_EA);

  mfma_argmin_kernel<<<NPT / 32, 128, 0, stream>>>(zh, zl, cbh, cbl,
                                                   wsf + WS_Y2, wsf + WS_X2,
                                                   z, cb,
                                                   (int*)(wsf + WS_IDX), out + OFF_CODES);

  gather_kernel<<<BDT / 256, 256, 0, stream>>>(z, cb, (int*)(wsf + WS_IDX),
                                               out + OFF_ZQ, out + OFF_EA,
                                               wsf + WS_COUNTS, wsf + WS_LOSS);
  cs_rand_kernel<<<KCB / 256, 256, 0, stream>>>(ema_cs, wsf + WS_COUNTS,
                                                wsf + WS_CS0, (uint32_t*)(wsf + WS_RAND),
                                                wsf + WS_NTOT);
  finalize_kernel<<<KD / 256, 256, 0, stream>>>(z, wsf + WS_CS0, (uint32_t*)(wsf + WS_RAND),
                                                wsf + WS_NTOT, wsf + WS_LOSS, out);
}

// Round 8
// 446.640 us; speedup vs baseline: 1.7033x; 1.0484x over previous
//
#include <hip/hip_runtime.h>
#include <stdint.h>

// Problem constants
#define KCB 4096
#define DIM 128
#define BSZ 8
#define TLEN 3000
#define NPT 24000            // BSZ*TLEN
#define KD (KCB*DIM)         // 524288
#define BDT (BSZ*DIM*TLEN)   // 3072000

// Output layout (floats, concatenated in reference return order)
#define OFF_ZQ    0
#define OFF_CODES 3072000
#define OFF_LOSS  3096000
#define OFF_CB    3096001
#define OFF_CS    3620289
#define OFF_EA    3624385

// Big scratch lives in d_out regions that are dead until later kernels:
//   zh/zl  -> [OFF_ZQ, OFF_ZQ+3072000)  (read by mfma + ea_scatter; z_q
//                                        written by zq_loss AFTER ea_scatter)
//   cbh/cbl-> [3096004, 3620292)        (new_codebook written by finalize LAST)
#define OUT_ZH    0            // float offset; ushort[24000*128] = 1,536,000 floats
#define OUT_ZL    1536000
#define OUT_CBH   3096004      // 16B-aligned; ushort[4096*128] = 262,144 floats
#define OUT_CBL   3358148

// Workspace layout (float units) — total ~64,400 floats = 258 KB
#define WS_LOSS   0
#define WS_NTOT   1
#define WS_COUNTS 16                     // 4096
#define WS_Y2     (WS_COUNTS + 4096)     // 4096
#define WS_X2     (WS_Y2 + 4096)         // 24000
#define WS_CS0    (WS_X2 + 24000)        // 4096
#define WS_RAND   (WS_CS0 + 4096)        // uint32[4096]
#define WS_IDX    (WS_RAND + 4096)       // int32[24000]

#define EPS_CAND 2e-3f
#define CAND_MAX 8

typedef __attribute__((ext_vector_type(8))) short bf16x8;
typedef __attribute__((ext_vector_type(4))) float f32x4;
typedef __attribute__((ext_vector_type(4))) int i32x4;

__device__ __forceinline__ unsigned short f2bf(float f) {
  uint32_t u = __float_as_uint(f);
  uint32_t r = (u + 0x7FFFu + ((u >> 16) & 1u)) >> 16;   // RNE
  return (unsigned short)r;
}
__device__ __forceinline__ float bf2f(unsigned short h) {
  return __uint_as_float(((uint32_t)h) << 16);
}

// ---------------- threefry2x32-20 (JAX-compatible) ----------------
__device__ __forceinline__ void threefry2x32(uint32_t k0, uint32_t k1,
                                             uint32_t x0, uint32_t x1,
                                             uint32_t& o0, uint32_t& o1) {
  const uint32_t ks0 = k0, ks1 = k1, ks2 = k0 ^ k1 ^ 0x1BD11BDAu;
  const int r0[4] = {13, 15, 26, 6};
  const int r1[4] = {17, 29, 16, 24};
  x0 += ks0; x1 += ks1;
  #pragma unroll
  for (int i = 0; i < 5; ++i) {
    #pragma unroll
    for (int j = 0; j < 4; ++j) {
      int r = (i & 1) ? r1[j] : r0[j];
      x0 += x1;
      x1 = (x1 << r) | (x1 >> (32 - r));
      x1 ^= x0;
    }
    uint32_t ia = (uint32_t)((i + 1) % 3), ib = (uint32_t)((i + 2) % 3);
    uint32_t a = (ia == 0) ? ks0 : (ia == 1) ? ks1 : ks2;
    uint32_t b = (ib == 0) ? ks0 : (ib == 1) ? ks1 : ks2;
    x0 += a;
    x1 += b + (uint32_t)(i + 1);
  }
  o0 = x0; o1 = x1;
}

// numpy pairwise sum-of-squares, n=128: 8 accumulators, separately-rounded
// products, combine ((r0+r1)+(r2+r3))+((r4+r5)+(r6+r7)).
__device__ __forceinline__ float np_sumsq_128(const float* __restrict__ v) {
  float r[8];
  #pragma unroll
  for (int j = 0; j < 8; ++j) r[j] = __fmul_rn(v[j], v[j]);
  #pragma unroll
  for (int i = 8; i < DIM; i += 8) {
    #pragma unroll
    for (int j = 0; j < 8; ++j)
      r[j] = __fadd_rn(r[j], __fmul_rn(v[i + j], v[i + j]));
  }
  return __fadd_rn(__fadd_rn(__fadd_rn(r[0], r[1]), __fadd_rn(r[2], r[3])),
                   __fadd_rn(__fadd_rn(r[4], r[5]), __fadd_rn(r[6], r[7])));
}

// ---------------- prep_z: transpose z -> bf16 hi/lo rows + np-exact x2 -----
__global__ void prep_z_kernel(const float* __restrict__ z,
                              unsigned short* __restrict__ zh,
                              unsigned short* __restrict__ zl,
                              float* __restrict__ x2) {
  __shared__ float zt[64 * 132];
  const int tid = threadIdx.x;
  const int n0 = blockIdx.x * 64;
  {
    int nl = tid & 63, dd = tid >> 6;
    int n = n0 + nl;
    int b = n / TLEN, t = n - b * TLEN;
    const float* zbase = z + (size_t)b * (DIM * TLEN) + t;
    #pragma unroll
    for (int d = dd; d < DIM; d += 4) zt[nl * 132 + d] = zbase[(size_t)d * TLEN];
  }
  __syncthreads();
  if (tid < 64) x2[n0 + tid] = np_sumsq_128(zt + tid * 132);

  int r = tid >> 2, d0 = (tid & 3) * 32;
  const float* src = zt + r * 132 + d0;
  size_t base = (size_t)(n0 + r) * 128 + d0;
  #pragma unroll
  for (int c = 0; c < 4; ++c) {
    i32x4 wh, wl;
    #pragma unroll
    for (int q = 0; q < 4; ++q) {
      float f0 = src[c * 8 + q * 2], f1 = src[c * 8 + q * 2 + 1];
      unsigned short h0 = f2bf(f0), h1 = f2bf(f1);
      unsigned short l0 = f2bf(f0 - bf2f(h0)), l1 = f2bf(f1 - bf2f(h1));
      wh[q] = (int)((uint32_t)h0 | ((uint32_t)h1 << 16));
      wl[q] = (int)((uint32_t)l0 | ((uint32_t)l1 << 16));
    }
    *(i32x4*)(zh + base + c * 8) = wh;
    *(i32x4*)(zl + base + c * 8) = wl;
  }
}

// ---------------- prep_cb: cb -> bf16 hi/lo + np-exact y2 ----------------
__global__ void prep_cb_kernel(const float* __restrict__ cb,
                               unsigned short* __restrict__ cbh,
                               unsigned short* __restrict__ cbl,
                               float* __restrict__ y2) {
  int k = blockIdx.x * 256 + threadIdx.x;
  const float4* row4 = (const float4*)(cb + (size_t)k * DIM);
  float racc[8];
  #pragma unroll
  for (int j = 0; j < 8; ++j) racc[j] = 0.f;
  #pragma unroll 4
  for (int c2 = 0; c2 < 16; ++c2) {
    float4 a = row4[c2 * 2], b = row4[c2 * 2 + 1];
    float f[8] = {a.x, a.y, a.z, a.w, b.x, b.y, b.z, b.w};
    i32x4 wh, wl;
    #pragma unroll
    for (int q = 0; q < 4; ++q) {
      float f0 = f[q * 2], f1 = f[q * 2 + 1];
      unsigned short h0 = f2bf(f0), h1 = f2bf(f1);
      unsigned short l0 = f2bf(f0 - bf2f(h0)), l1 = f2bf(f1 - bf2f(h1));
      wh[q] = (int)((uint32_t)h0 | ((uint32_t)h1 << 16));
      wl[q] = (int)((uint32_t)l0 | ((uint32_t)l1 << 16));
    }
    *(i32x4*)(cbh + (size_t)k * DIM + c2 * 8) = wh;
    *(i32x4*)(cbl + (size_t)k * DIM + c2 * 8) = wl;
    #pragma unroll
    for (int j = 0; j < 8; ++j)
      racc[j] = __fadd_rn(racc[j], __fmul_rn(f[j], f[j]));
  }
  y2[k] = __fadd_rn(__fadd_rn(__fadd_rn(racc[0], racc[1]), __fadd_rn(racc[2], racc[3])),
                    __fadd_rn(__fadd_rn(racc[4], racc[5]), __fadd_rn(racc[6], racc[7])));
}

// ---------------- ea_init ----------------
__global__ void ea_init_kernel(const float* __restrict__ ema_ea, float* __restrict__ out_ea) {
  int i = blockIdx.x * 256 + threadIdx.x;
  out_ea[i] = 0.99f * ema_ea[i];
}

// ---------------- MFMA argmin: 750 blocks x 128 thr; 32n/block, full-K ------
// approx key(n,k) = y2[k] - 2*dot via 3-term bf16-split MFMA (hh+hl+lh; the
// ll term is <= ~3e-5, inside the EPS_CAND=2e-3 budget with 4x margin).
// Per-lane top-3 over INDIVIDUAL k distances -> candidates within EPS ->
// exact np-fp32 rescore (ascending k, strict <).
__launch_bounds__(128)
__global__ void mfma_argmin_kernel(const unsigned short* __restrict__ zh,
                                   const unsigned short* __restrict__ zl,
                                   const unsigned short* __restrict__ cbh,
                                   const unsigned short* __restrict__ cbl,
                                   const float* __restrict__ y2g,
                                   const float* __restrict__ x2g,
                                   const float* __restrict__ z,
                                   const float* __restrict__ cb,
                                   int* __restrict__ idx_out,
                                   float* __restrict__ codes_out) {
  __shared__ alignas(16) unsigned short zh_t[32 * 128];   // swizzled [n][d]
  __shared__ alignas(16) unsigned short zl_t[32 * 128];
  __shared__ alignas(16) unsigned short ch_t[64 * 128];   // swizzled [k][d]
  __shared__ alignas(16) unsigned short cl_t[64 * 128];
  __shared__ alignas(16) float y2s[64];

  const int tid = threadIdx.x;
  const int wv = tid >> 6, lane = tid & 63;
  const int lg = lane >> 4, lc = lane & 15;
  const int n0 = blockIdx.x * 32;

  // stage z tiles once (chunk = 16B = 8 bf16; swizzle: chunk ^= row&7)
  {
    int r = tid >> 2, c0 = (tid & 3) * 4;
    const i32x4* gh = (const i32x4*)(zh + (size_t)(n0 + r) * 128);
    const i32x4* gl = (const i32x4*)(zl + (size_t)(n0 + r) * 128);
    #pragma unroll
    for (int c = 0; c < 4; ++c) {
      int cc = (c0 + c) ^ (r & 7);
      ((i32x4*)zh_t)[r * 16 + cc] = gh[c0 + c];
      ((i32x4*)zl_t)[r * 16 + cc] = gl[c0 + c];
    }
  }

  // codebook staging map: row = tid>>1 (0..63), 8 chunks starting (tid&1)*8
  const int srow = tid >> 1, sh = (tid & 1) * 8;
  i32x4 rbh[8], rbl[8];
  {
    const i32x4* gh = (const i32x4*)(cbh + (size_t)srow * 128);
    const i32x4* gl = (const i32x4*)(cbl + (size_t)srow * 128);
    #pragma unroll
    for (int c = 0; c < 8; ++c) { rbh[c] = gh[sh + c]; rbl[c] = gl[sh + c]; }
  }

  float t1v[2], t2v[2], t3v[2];
  int   t1i[2], t2i[2], t3i[2];
  #pragma unroll
  for (int ns = 0; ns < 2; ++ns) {
    t1v[ns] = t2v[ns] = t3v[ns] = 3.402823466e+38f;
    t1i[ns] = t2i[ns] = t3i[ns] = 0x7FFFFFFF;
  }

  for (int rd = 0; rd < KCB / 64; ++rd) {
    #pragma unroll
    for (int c = 0; c < 8; ++c) {
      int cc = (sh + c) ^ (srow & 7);
      ((i32x4*)ch_t)[srow * 16 + cc] = rbh[c];
      ((i32x4*)cl_t)[srow * 16 + cc] = rbl[c];
    }
    if (tid < 16) ((float4*)y2s)[tid] = ((const float4*)(y2g + rd * 64))[tid];
    __syncthreads();

    if (rd + 1 < KCB / 64) {
      const i32x4* gh = (const i32x4*)(cbh + (size_t)((rd + 1) * 64 + srow) * 128);
      const i32x4* gl = (const i32x4*)(cbl + (size_t)((rd + 1) * 64 + srow) * 128);
      #pragma unroll
      for (int c = 0; c < 8; ++c) { rbh[c] = gh[sh + c]; rbl[c] = gl[sh + c]; }
    }

    f32x4 acc[2][2];   // [nsub][ksub]
    #pragma unroll
    for (int ns = 0; ns < 2; ++ns)
      #pragma unroll
      for (int ks = 0; ks < 2; ++ks) acc[ns][ks] = 0.f;

    #pragma unroll
    for (int ds = 0; ds < 4; ++ds) {
      bf16x8 ah[2], al[2], bh[2], bl[2];
      #pragma unroll
      for (int ks = 0; ks < 2; ++ks) {
        int row = wv * 32 + ks * 16 + lc;
        int cc = (ds * 4 + lg) ^ (row & 7);
        ah[ks] = *(const bf16x8*)&ch_t[row * 128 + cc * 8];
        al[ks] = *(const bf16x8*)&cl_t[row * 128 + cc * 8];
      }
      #pragma unroll
      for (int ns = 0; ns < 2; ++ns) {
        int row = ns * 16 + lc;
        int cc = (ds * 4 + lg) ^ (row & 7);
        bh[ns] = *(const bf16x8*)&zh_t[row * 128 + cc * 8];
        bl[ns] = *(const bf16x8*)&zl_t[row * 128 + cc * 8];
      }
      #pragma unroll
      for (int ns = 0; ns < 2; ++ns)
        #pragma unroll
        for (int ks = 0; ks < 2; ++ks) {
          acc[ns][ks] = __builtin_amdgcn_mfma_f32_16x16x32_bf16(ah[ks], bh[ns], acc[ns][ks], 0, 0, 0);
          acc[ns][ks] = __builtin_amdgcn_mfma_f32_16x16x32_bf16(ah[ks], bl[ns], acc[ns][ks], 0, 0, 0);
          acc[ns][ks] = __builtin_amdgcn_mfma_f32_16x16x32_bf16(al[ks], bh[ns], acc[ns][ks], 0, 0, 0);
        }
    }

    // distances + per-lane top-3 over INDIVIDUAL k (no frag compression)
    #pragma unroll
    for (int ks = 0; ks < 2; ++ks) {
      int klocal = wv * 32 + ks * 16 + lg * 4;
      float4 y4 = *(const float4*)&y2s[klocal];
      int kbase = rd * 64 + klocal;
      #pragma unroll
      for (int ns = 0; ns < 2; ++ns) {
        float dv[4];
        dv[0] = fmaf(-2.f, acc[ns][ks][0], y4.x);
        dv[1] = fmaf(-2.f, acc[ns][ks][1], y4.y);
        dv[2] = fmaf(-2.f, acc[ns][ks][2], y4.z);
        dv[3] = fmaf(-2.f, acc[ns][ks][3], y4.w);
        #pragma unroll
        for (int q = 0; q < 4; ++q) {
          float v = dv[q];
          int kidx = kbase + q;
          bool c1 = v < t1v[ns], c2 = v < t2v[ns], c3 = v < t3v[ns];
          float n3v = c2 ? t2v[ns] : (c3 ? v : t3v[ns]);
          int   n3i = c2 ? t2i[ns] : (c3 ? kidx : t3i[ns]);
          float n2v = c1 ? t1v[ns] : (c2 ? v : t2v[ns]);
          int   n2i = c1 ? t1i[ns] : (c2 ? kidx : t2i[ns]);
          t1v[ns] = c1 ? v : t1v[ns]; t1i[ns] = c1 ? kidx : t1i[ns];
          t2v[ns] = n2v; t2i[ns] = n2i;
          t3v[ns] = n3v; t3i[ns] = n3i;
        }
      }
    }
    __syncthreads();
  }

  // ---- tail: merge 8 per-lane lists per row, candidates, exact rescore
  float* tv = (float*)ch_t;   // 32n * 8 lists * 3
  int*   ti = (int*)cl_t;
  #pragma unroll
  for (int ns = 0; ns < 2; ++ns) {
    int nl = ns * 16 + lc;
    int base = (nl * 8 + wv * 4 + lg) * 3;
    tv[base + 0] = t1v[ns]; ti[base + 0] = t1i[ns];
    tv[base + 1] = t2v[ns]; ti[base + 1] = t2i[ns];
    tv[base + 2] = t3v[ns]; ti[base + 2] = t3i[ns];
  }
  __syncthreads();

  if (tid < 32) {
    int n = n0 + tid;
    float bv = 3.402823466e+38f; int bi = 0x7FFFFFFF;
    for (int e = 0; e < 24; ++e) {
      float v = tv[tid * 24 + e]; int i2 = ti[tid * 24 + e];
      if (v < bv || (v == bv && i2 < bi)) { bv = v; bi = i2; }
    }
    int ci[CAND_MAX]; int cnt = 0;
    float lim = bv + EPS_CAND;
    for (int e = 0; e < 24; ++e) {
      float v = tv[tid * 24 + e];
      if (v <= lim && cnt < CAND_MAX) {
        int x = ti[tid * 24 + e];
        int p = cnt++;
        while (p > 0 && ci[p - 1] > x) { ci[p] = ci[p - 1]; --p; }
        ci[p] = x;
      }
    }
    int kbest = ci[0];
    if (cnt > 1) {
      int b = n / TLEN, t = n - b * TLEN;
      const float* zr = z + (size_t)b * (DIM * TLEN) + t;
      float bestv = 0.f;
      for (int c = 0; c < cnt; ++c) {
        int k = ci[c];
        const float* cr = cb + (size_t)k * DIM;
        float dot = 0.f;
        for (int d = 0; d < DIM; ++d)
          dot = __fmaf_rn(zr[(size_t)d * TLEN], cr[d], dot);
        float tt = __fadd_rn(x2g[n], y2g[k]);
        float dist = __fsub_rn(tt, __fmul_rn(2.0f, dot));
        if (c == 0 || dist < bestv) { bestv = dist; kbest = k; }
      }
    }
    idx_out[n] = kbest;
    codes_out[n] = (float)kbest;
  }
}

// ---------------- ea_scatter: one WAVE per row n — coalesced EA atomics ----
// z reconstructed from zh+zl (err <= 2^-17 * |z|; EA tolerance ~1e-2).
// atomics land on 512 contiguous bytes of ea_out[k] per wave.
__global__ void ea_scatter_kernel(const unsigned short* __restrict__ zh,
                                  const unsigned short* __restrict__ zl,
                                  const int* __restrict__ idx,
                                  float* __restrict__ ea_out,
                                  float* __restrict__ counts) {
  int n = (blockIdx.x * 256 + threadIdx.x) >> 6;   // wave id == row
  int lane = threadIdx.x & 63;
  int k = idx[n];
  uint32_t h = *(const uint32_t*)(zh + (size_t)n * 128 + lane * 2);
  uint32_t l = *(const uint32_t*)(zl + (size_t)n * 128 + lane * 2);
  float f0 = bf2f((unsigned short)(h & 0xffffu)) + bf2f((unsigned short)(l & 0xffffu));
  float f1 = bf2f((unsigned short)(h >> 16)) + bf2f((unsigned short)(l >> 16));
  float* dst = ea_out + (size_t)k * DIM + lane * 2;
  atomicAdd(dst, 0.01f * f0);
  atomicAdd(dst + 1, 0.01f * f1);
  if (lane == 0) atomicAdd(counts + k, 1.0f);
}

// ---------------- zq_loss: coalesced z_q gather + commit-loss (no scatter) --
__global__ void zq_loss_kernel(const float* __restrict__ z, const float* __restrict__ cb,
                               const int* __restrict__ idx,
                               float* __restrict__ zq_out, float* __restrict__ loss_ws) {
  int i = blockIdx.x * 256 + threadIdx.x;   // [B][D][T]
  int t = i % TLEN;
  int bd = i / TLEN;
  int d = bd & (DIM - 1);
  int b = bd >> 7;
  int n = b * TLEN + t;
  int k = idx[n];
  float zv = z[i];
  float q = cb[(size_t)k * DIM + d];
  zq_out[i] = q;
  float diff = zv - q;
  float sq = diff * diff;
  #pragma unroll
  for (int m = 1; m <= 32; m <<= 1) sq += __shfl_xor(sq, m);
  __shared__ float ps[4];
  if ((threadIdx.x & 63) == 0) ps[threadIdx.x >> 6] = sq;
  __syncthreads();
  if (threadIdx.x == 0) atomicAdd(loss_ws, ps[0] + ps[1] + ps[2] + ps[3]);
}

// ---------------- cs_rand ----------------
__global__ void cs_rand_kernel(const float* __restrict__ ema_cs, const float* __restrict__ counts,
                               float* __restrict__ cs0, uint32_t* __restrict__ rnd,
                               float* __restrict__ ntot) {
  int k = blockIdx.x * 256 + threadIdx.x;
  float v = 0.99f * ema_cs[k] + 0.01f * counts[k];
  cs0[k] = v;

  uint32_t o0, o1;
  threefry2x32(0u, 42u, 0u, (uint32_t)k, o0, o1);
  uint32_t bits = o0 ^ o1;
  uint32_t hi = bits >> 16, lo = bits & 0xffffu;
  const uint32_t span = 24000u, mult = 23296u;  // 2^32 % 24000
  uint32_t off = ((hi % span) * mult + (lo % span)) % span;
  rnd[k] = off;

  float s = v;
  #pragma unroll
  for (int m = 1; m <= 32; m <<= 1) s += __shfl_xor(s, m);
  __shared__ float ps[4];
  if ((threadIdx.x & 63) == 0) ps[threadIdx.x >> 6] = s;
  __syncthreads();
  if (threadIdx.x == 0) atomicAdd(ntot, ps[0] + ps[1] + ps[2] + ps[3]);
}

// ---------------- finalize ----------------
__global__ void finalize_kernel(const float* __restrict__ z, const float* __restrict__ cs0_ws,
                                const uint32_t* __restrict__ rnd,
                                const float* __restrict__ ntot_ws, const float* __restrict__ loss_ws,
                                float* __restrict__ out) {
  int i = blockIdx.x * 256 + threadIdx.x;   // i < KD
  int k = i >> 7, d = i & (DIM - 1);
  float cs0 = cs0_ws[k];
  float ntot = *ntot_ws;
  float* ea = out + OFF_EA;
  float ea0 = ea[i];
  float csz = (cs0 + 1e-5f) / (ntot + (float)KCB * 1e-5f) * ntot;
  float embed = ea0 / fmaxf(csz, 1e-12f);
  bool dead = cs0 < 2.0f;
  uint32_t rn = rnd[k];
  int bb = (int)(rn / TLEN), tt = (int)(rn % TLEN);
  float sampled = z[(size_t)bb * (DIM * TLEN) + (size_t)d * TLEN + tt];
  out[OFF_CB + i] = dead ? sampled : embed;
  ea[i] = dead ? sampled : ea0;
  if (d == 0) out[OFF_CS + k] = dead ? 1.0f : cs0;
  if (i == 0) out[OFF_LOSS] = (*loss_ws) * (1.0f / (float)BDT);
}

extern "C" void kernel_launch(void* const* d_in, const int* in_sizes, int n_in,
                              void* d_out, int out_size, void* d_ws, size_t ws_size,
                              hipStream_t stream) {
  const float* z      = (const float*)d_in[0];
  const float* cb     = (const float*)d_in[1];
  const float* ema_cs = (const float*)d_in[2];
  const float* ema_ea = (const float*)d_in[3];
  float* out = (float*)d_out;
  float* wsf = (float*)d_ws;

  unsigned short* zh  = (unsigned short*)(out + OUT_ZH);
  unsigned short* zl  = (unsigned short*)(out + OUT_ZL);
  unsigned short* cbh = (unsigned short*)(out + OUT_CBH);
  unsigned short* cbl = (unsigned short*)(out + OUT_CBL);

  hipMemsetAsync(d_ws, 0, (size_t)(16 + 4096) * sizeof(float), stream);

  prep_cb_kernel<<<KCB / 256, 256, 0, stream>>>(cb, cbh, cbl, wsf + WS_Y2);
  prep_z_kernel<<<NPT / 64, 256, 0, stream>>>(z, zh, zl, wsf + WS_X2);
  ea_init_kernel<<<KD / 256, 256, 0, stream>>>(ema_ea, out + OFF_EA);

  mfma_argmin_kernel<<<NPT / 32, 128, 0, stream>>>(zh, zl, cbh, cbl,
                                                   wsf + WS_Y2, wsf + WS_X2,
                                                   z, cb,
                                                   (int*)(wsf + WS_IDX), out + OFF_CODES);

  // ea_scatter reads zh/zl (z_q region) -> MUST run before zq_loss overwrites it
  ea_scatter_kernel<<<NPT * 64 / 256, 256, 0, stream>>>(zh, zl, (int*)(wsf + WS_IDX),
                                                        out + OFF_EA, wsf + WS_COUNTS);
  zq_loss_kernel<<<BDT / 256, 256, 0, stream>>>(z, cb, (int*)(wsf + WS_IDX),
                                                out + OFF_ZQ, wsf + WS_LOSS);
  cs_rand_kernel<<<KCB / 256, 256, 0, stream>>>(ema_cs, wsf + WS_COUNTS,
                                                wsf + WS_CS0, (uint32_t*)(wsf + WS_RAND),
                                                wsf + WS_NTOT);
  finalize_kernel<<<KD / 256, 256, 0, stream>>>(z, wsf + WS_CS0, (uint32_t*)(wsf + WS_RAND),
                                                wsf + WS_NTOT, wsf + WS_LOSS, out);
}